// Round 1
// baseline (4121.048 us; speedup 1.0000x reference)
//
#include <hip/hip_runtime.h>
#include <hip/hip_bf16.h>
#include <stdint.h>

#define N_NODES 50000
#define N_EDGES 800000
#define D 128
#define NLAYER 3

typedef __attribute__((ext_vector_type(8))) short bf16x8;
typedef __attribute__((ext_vector_type(4))) float f32x4;

__device__ __forceinline__ short f2bf(float f) {
    union { float f; uint32_t u; } v; v.f = f;
    uint32_t u = v.u;
    uint32_t r = u + 0x7fffu + ((u >> 16) & 1u);   // round-to-nearest-even
    return (short)(r >> 16);
}

// ---------------------------------------------------------------------------
// Convert W1/W2 (all layers) to bf16 in B-fragment-swizzled layout:
// Wswz[((l*2+mat)*4 + ks)*8 + nt][lane][j] = W[l][ks*32 + (lane>>4)*8 + j][nt*16 + (lane&15)]
// so each lane's B-frag for (ks,nt) is 8 contiguous bf16 (one 16B load).
// ---------------------------------------------------------------------------
__global__ void wconv(const float* __restrict__ W1, const float* __restrict__ W2,
                      short* __restrict__ Wswz) {
    int t = blockIdx.x * blockDim.x + threadIdx.x;   // one per (l,mat,ks,nt,lane)
    if (t >= NLAYER * 2 * 4 * 8 * 64) return;
    int lane = t & 63;
    int nt   = (t >> 6) & 7;
    int ks   = (t >> 9) & 3;
    int mat  = (t >> 11) & 1;
    int l    = t >> 12;
    const float* W = (mat == 0 ? W1 : W2) + (size_t)l * D * D;
    int n = nt * 16 + (lane & 15);
    short* outp = Wswz + (size_t)t * 8;
#pragma unroll
    for (int j = 0; j < 8; ++j) {
        int k = ks * 32 + (lane >> 4) * 8 + j;
        outp[j] = f2bf(W[k * D + n]);
    }
}

// z = (1 + eps[l]) * h
__global__ void init_z(const float* __restrict__ h, float* __restrict__ z,
                       const float* __restrict__ eps, int l) {
    int t = blockIdx.x * blockDim.x + threadIdx.x;
    if (t >= N_NODES * D / 4) return;
    float s = 1.0f + eps[l];
    f32x4 v = ((const f32x4*)h)[t];
    ((f32x4*)z)[t] = v * s;
}

// z[dst[e]] += h[src[e]]  — thread per (edge, 4-float chunk)
__global__ void scatter(const float* __restrict__ h, const int* __restrict__ src,
                        const int* __restrict__ dst, float* __restrict__ z) {
    int t = blockIdx.x * blockDim.x + threadIdx.x;
    int e = t >> 5;
    if (e >= N_EDGES) return;
    int c = (t & 31) << 2;
    int s = src[e], d = dst[e];
    const float4 v = *(const float4*)(h + (size_t)s * D + c);
    float* zp = z + (size_t)d * D + c;
    atomicAdd(zp + 0, v.x);
    atomicAdd(zp + 1, v.y);
    atomicAdd(zp + 2, v.z);
    atomicAdd(zp + 3, v.w);
}

// ---------------------------------------------------------------------------
// Fused MLP: out = relu(z @ W1 + b1) @ W2 + b2.
// 4 waves/block, each wave owns 16 rows x full N=128.
// Stage-1 result staged per-wave in LDS (bf16, XOR swizzle) for stage-2 A-frags.
// ---------------------------------------------------------------------------
__global__ __launch_bounds__(256) void mlp(const float* __restrict__ z,
                                           const short* __restrict__ Wl,   // layer's W1 block; W2 at +16384
                                           const float* __restrict__ b1,
                                           const float* __restrict__ b2,
                                           float* __restrict__ out) {
    __shared__ short hlds[4][16 * 128];
    const int lane = threadIdx.x & 63;
    const int wid  = threadIdx.x >> 6;
    const int rowbase = (blockIdx.x * 4 + wid) * 16;
    if (rowbase >= N_NODES) return;           // wave-uniform exit; no __syncthreads used
    const int r0 = lane & 15;                 // A row / C col index
    const int kh = lane >> 4;                 // 0..3
    const int row = rowbase + r0;
    const int zrow = (row < N_NODES) ? row : (N_NODES - 1);
    short* hl = hlds[wid];

    // ---- stage 1: hid = relu(z @ W1 + b1) ----
    f32x4 acc[8];
#pragma unroll
    for (int nt = 0; nt < 8; ++nt) acc[nt] = (f32x4)(0.0f);

#pragma unroll
    for (int ks = 0; ks < 4; ++ks) {
        const float* zp = z + (size_t)zrow * D + ks * 32 + kh * 8;
        f32x4 a0 = *(const f32x4*)zp;
        f32x4 a1 = *(const f32x4*)(zp + 4);
        bf16x8 af;
        af[0] = f2bf(a0.x); af[1] = f2bf(a0.y); af[2] = f2bf(a0.z); af[3] = f2bf(a0.w);
        af[4] = f2bf(a1.x); af[5] = f2bf(a1.y); af[6] = f2bf(a1.z); af[7] = f2bf(a1.w);
        const short* wp = Wl + ((size_t)(ks * 8) * 64 + lane) * 8;
#pragma unroll
        for (int nt = 0; nt < 8; ++nt) {
            bf16x8 bf = *(const bf16x8*)(wp + (size_t)nt * 64 * 8);
            acc[nt] = __builtin_amdgcn_mfma_f32_16x16x32_bf16(af, bf, acc[nt], 0, 0, 0);
        }
    }

    // bias + relu -> LDS (bf16), swizzled: elem col ^= (row&7)<<3  (16B-granular XOR)
#pragma unroll
    for (int nt = 0; nt < 8; ++nt) {
        int col = nt * 16 + r0;
        float bias = b1[col];
#pragma unroll
        for (int r = 0; r < 4; ++r) {
            int hrow = kh * 4 + r;
            float v = fmaxf(acc[nt][r] + bias, 0.0f);
            hl[hrow * 128 + (col ^ ((hrow & 7) << 3))] = f2bf(v);
        }
    }
    asm volatile("s_waitcnt lgkmcnt(0)" ::: "memory");

    // ---- stage 2: out = hid @ W2 + b2 ----
    f32x4 acc2[8];
#pragma unroll
    for (int nt = 0; nt < 8; ++nt) acc2[nt] = (f32x4)(0.0f);

    const short* W2p = Wl + 4 * 8 * 64 * 8;   // +16384 shorts
#pragma unroll
    for (int ks = 0; ks < 4; ++ks) {
        int c0 = ks * 32 + kh * 8;
        bf16x8 af = *(const bf16x8*)&hl[r0 * 128 + (c0 ^ ((r0 & 7) << 3))];
        const short* wp = W2p + ((size_t)(ks * 8) * 64 + lane) * 8;
#pragma unroll
        for (int nt = 0; nt < 8; ++nt) {
            bf16x8 bf = *(const bf16x8*)(wp + (size_t)nt * 64 * 8);
            acc2[nt] = __builtin_amdgcn_mfma_f32_16x16x32_bf16(af, bf, acc2[nt], 0, 0, 0);
        }
    }

#pragma unroll
    for (int nt = 0; nt < 8; ++nt) {
        int col = nt * 16 + r0;
        float bias = b2[col];
#pragma unroll
        for (int r = 0; r < 4; ++r) {
            int orow = rowbase + kh * 4 + r;
            if (orow < N_NODES) out[(size_t)orow * D + col] = acc2[nt][r] + bias;
        }
    }
}

extern "C" void kernel_launch(void* const* d_in, const int* in_sizes, int n_in,
                              void* d_out, int out_size, void* d_ws, size_t ws_size,
                              hipStream_t stream) {
    const float* h   = (const float*)d_in[0];
    const int*   src = (const int*)d_in[1];
    const int*   dst = (const int*)d_in[2];
    const float* W1  = (const float*)d_in[3];
    const float* b1  = (const float*)d_in[4];
    const float* W2  = (const float*)d_in[5];
    const float* b2  = (const float*)d_in[6];
    const float* eps = (const float*)d_in[7];
    float* out = (float*)d_out;

    char* ws = (char*)d_ws;
    float* z   = (float*)ws;                          // 25.6 MB
    float* h2  = (float*)(ws + (size_t)26 * 1024 * 1024);  // 25.6 MB
    short* Wswz = (short*)(ws + (size_t)52 * 1024 * 1024); // 196 KB

    wconv<<<48, 256, 0, stream>>>(W1, W2, Wswz);

    const float* hin[3] = {h, out, h2};
    float*      hout[3] = {out, h2, out};
    const int z_blocks  = (N_NODES * D / 4 + 255) / 256;
    const int sc_blocks = (N_EDGES * 32) / 256;
    const int mm_blocks = (N_NODES + 63) / 64;

    for (int l = 0; l < NLAYER; ++l) {
        init_z<<<z_blocks, 256, 0, stream>>>(hin[l], z, eps, l);
        scatter<<<sc_blocks, 256, 0, stream>>>(hin[l], src, dst, z);
        mlp<<<mm_blocks, 256, 0, stream>>>(z, Wswz + (size_t)l * 2 * 16384,
                                           b1 + (size_t)l * D, b2 + (size_t)l * D, hout[l]);
    }
}

// Round 2
// 358.791 us; speedup vs baseline: 11.4859x; 11.4859x over previous
//
#include <hip/hip_runtime.h>
#include <hip/hip_bf16.h>
#include <stdint.h>

#define N_NODES 50000
#define N_EDGES 800000
#define D 128
#define NLAYER 3
#define SCAN_NB ((N_NODES + 255) / 256)   // 196

typedef __attribute__((ext_vector_type(8))) short bf16x8;
typedef __attribute__((ext_vector_type(4))) float f32x4;

__device__ __forceinline__ short f2bf(float f) {
    union { float f; uint32_t u; } v; v.f = f;
    uint32_t u = v.u;
    uint32_t r = u + 0x7fffu + ((u >> 16) & 1u);   // round-to-nearest-even
    return (short)(r >> 16);
}

// ---------------------------------------------------------------------------
// Weight conversion: bf16, B-fragment-swizzled (one 16B load per lane-frag).
// ---------------------------------------------------------------------------
__global__ void wconv(const float* __restrict__ W1, const float* __restrict__ W2,
                      short* __restrict__ Wswz) {
    int t = blockIdx.x * blockDim.x + threadIdx.x;   // (l,mat,ks,nt,lane)
    if (t >= NLAYER * 2 * 4 * 8 * 64) return;
    int lane = t & 63;
    int nt   = (t >> 6) & 7;
    int ks   = (t >> 9) & 3;
    int mat  = (t >> 11) & 1;
    int l    = t >> 12;
    const float* W = (mat == 0 ? W1 : W2) + (size_t)l * D * D;
    int n = nt * 16 + (lane & 15);
    short* outp = Wswz + (size_t)t * 8;
#pragma unroll
    for (int j = 0; j < 8; ++j) {
        int k = ks * 32 + (lane >> 4) * 8 + j;
        outp[j] = f2bf(W[k * D + n]);
    }
}

// ---------------------------------------------------------------------------
// CSR build: zero -> histogram -> 3-kernel exclusive scan -> fill
// ---------------------------------------------------------------------------
__global__ void zero_off(int* __restrict__ off) {
    int i = blockIdx.x * blockDim.x + threadIdx.x;
    if (i <= N_NODES) off[i] = 0;
}

__global__ void hist(const int* __restrict__ dst, int* __restrict__ off) {
    int e = blockIdx.x * blockDim.x + threadIdx.x;
    if (e < N_EDGES) atomicAdd(&off[dst[e]], 1);
}

__global__ void scan_block(int* __restrict__ off, int* __restrict__ bsum) {
    __shared__ int tmp[256];
    int i = blockIdx.x * 256 + threadIdx.x;
    int v = (i < N_NODES) ? off[i] : 0;
    tmp[threadIdx.x] = v;
    __syncthreads();
#pragma unroll
    for (int s = 1; s < 256; s <<= 1) {
        int t = (threadIdx.x >= s) ? tmp[threadIdx.x - s] : 0;
        __syncthreads();
        tmp[threadIdx.x] += t;
        __syncthreads();
    }
    if (i < N_NODES) off[i] = tmp[threadIdx.x] - v;      // exclusive within block
    if (threadIdx.x == 255) bsum[blockIdx.x] = tmp[255]; // block total
}

__global__ void scan_bsum(int* __restrict__ bsum) {
    __shared__ int tmp[256];
    int v = (threadIdx.x < SCAN_NB) ? bsum[threadIdx.x] : 0;
    tmp[threadIdx.x] = v;
    __syncthreads();
#pragma unroll
    for (int s = 1; s < 256; s <<= 1) {
        int t = (threadIdx.x >= s) ? tmp[threadIdx.x - s] : 0;
        __syncthreads();
        tmp[threadIdx.x] += t;
        __syncthreads();
    }
    if (threadIdx.x < SCAN_NB) bsum[threadIdx.x] = tmp[threadIdx.x] - v; // exclusive
}

__global__ void scan_add(int* __restrict__ off, const int* __restrict__ bsum,
                         int* __restrict__ cursor) {
    int i = blockIdx.x * 256 + threadIdx.x;
    if (i < N_NODES) {
        int o = off[i] + bsum[blockIdx.x];
        off[i] = o;
        cursor[i] = o;
    }
    if (i == 0) off[N_NODES] = N_EDGES;
}

__global__ void fill(const int* __restrict__ src, const int* __restrict__ dst,
                     int* __restrict__ cursor, int* __restrict__ esrc) {
    int e = blockIdx.x * blockDim.x + threadIdx.x;
    if (e < N_EDGES) {
        int p = atomicAdd(&cursor[dst[e]], 1);
        esrc[p] = src[e];
    }
}

// ---------------------------------------------------------------------------
// Pull aggregation fused with (1+eps)*h: one wave per node, float2 per lane.
// ---------------------------------------------------------------------------
__global__ __launch_bounds__(256) void aggregate(const float* __restrict__ h,
                                                 const int* __restrict__ off,
                                                 const int* __restrict__ esrc,
                                                 float* __restrict__ z,
                                                 const float* __restrict__ eps, int l) {
    int gw = (blockIdx.x * 256 + threadIdx.x) >> 6;   // global wave id = node
    int lane = threadIdx.x & 63;
    if (gw >= N_NODES) return;
    const float s = 1.0f + eps[l];
    float2 acc = ((const float2*)(h + (size_t)gw * D))[lane];
    acc.x *= s; acc.y *= s;
    int j = off[gw], end = off[gw + 1];
    // unroll-by-2 for a little more MLP (memory-level parallelism)
    for (; j + 1 < end; j += 2) {
        int u0 = esrc[j], u1 = esrc[j + 1];
        float2 t0 = ((const float2*)(h + (size_t)u0 * D))[lane];
        float2 t1 = ((const float2*)(h + (size_t)u1 * D))[lane];
        acc.x += t0.x + t1.x;
        acc.y += t0.y + t1.y;
    }
    if (j < end) {
        int u = esrc[j];
        float2 t = ((const float2*)(h + (size_t)u * D))[lane];
        acc.x += t.x; acc.y += t.y;
    }
    ((float2*)(z + (size_t)gw * D))[lane] = acc;
}

// ---------------------------------------------------------------------------
// Fused MLP: out = relu(z @ W1 + b1) @ W2 + b2.  (unchanged from R1)
// ---------------------------------------------------------------------------
__global__ __launch_bounds__(256) void mlp(const float* __restrict__ z,
                                           const short* __restrict__ Wl,
                                           const float* __restrict__ b1,
                                           const float* __restrict__ b2,
                                           float* __restrict__ out) {
    __shared__ short hlds[4][16 * 128];
    const int lane = threadIdx.x & 63;
    const int wid  = threadIdx.x >> 6;
    const int rowbase = (blockIdx.x * 4 + wid) * 16;
    if (rowbase >= N_NODES) return;           // wave-uniform exit; no __syncthreads used
    const int r0 = lane & 15;
    const int kh = lane >> 4;
    const int row = rowbase + r0;
    const int zrow = (row < N_NODES) ? row : (N_NODES - 1);
    short* hl = hlds[wid];

    f32x4 acc[8];
#pragma unroll
    for (int nt = 0; nt < 8; ++nt) acc[nt] = (f32x4)(0.0f);

#pragma unroll
    for (int ks = 0; ks < 4; ++ks) {
        const float* zp = z + (size_t)zrow * D + ks * 32 + kh * 8;
        f32x4 a0 = *(const f32x4*)zp;
        f32x4 a1 = *(const f32x4*)(zp + 4);
        bf16x8 af;
        af[0] = f2bf(a0.x); af[1] = f2bf(a0.y); af[2] = f2bf(a0.z); af[3] = f2bf(a0.w);
        af[4] = f2bf(a1.x); af[5] = f2bf(a1.y); af[6] = f2bf(a1.z); af[7] = f2bf(a1.w);
        const short* wp = Wl + ((size_t)(ks * 8) * 64 + lane) * 8;
#pragma unroll
        for (int nt = 0; nt < 8; ++nt) {
            bf16x8 bf = *(const bf16x8*)(wp + (size_t)nt * 64 * 8);
            acc[nt] = __builtin_amdgcn_mfma_f32_16x16x32_bf16(af, bf, acc[nt], 0, 0, 0);
        }
    }

#pragma unroll
    for (int nt = 0; nt < 8; ++nt) {
        int col = nt * 16 + r0;
        float bias = b1[col];
#pragma unroll
        for (int r = 0; r < 4; ++r) {
            int hrow = kh * 4 + r;
            float v = fmaxf(acc[nt][r] + bias, 0.0f);
            hl[hrow * 128 + (col ^ ((hrow & 7) << 3))] = f2bf(v);
        }
    }
    asm volatile("s_waitcnt lgkmcnt(0)" ::: "memory");

    f32x4 acc2[8];
#pragma unroll
    for (int nt = 0; nt < 8; ++nt) acc2[nt] = (f32x4)(0.0f);

    const short* W2p = Wl + 4 * 8 * 64 * 8;
#pragma unroll
    for (int ks = 0; ks < 4; ++ks) {
        int c0 = ks * 32 + kh * 8;
        bf16x8 af = *(const bf16x8*)&hl[r0 * 128 + (c0 ^ ((r0 & 7) << 3))];
        const short* wp = W2p + ((size_t)(ks * 8) * 64 + lane) * 8;
#pragma unroll
        for (int nt = 0; nt < 8; ++nt) {
            bf16x8 bf = *(const bf16x8*)(wp + (size_t)nt * 64 * 8);
            acc2[nt] = __builtin_amdgcn_mfma_f32_16x16x32_bf16(af, bf, acc2[nt], 0, 0, 0);
        }
    }

#pragma unroll
    for (int nt = 0; nt < 8; ++nt) {
        int col = nt * 16 + r0;
        float bias = b2[col];
#pragma unroll
        for (int r = 0; r < 4; ++r) {
            int orow = rowbase + kh * 4 + r;
            if (orow < N_NODES) out[(size_t)orow * D + col] = acc2[nt][r] + bias;
        }
    }
}

extern "C" void kernel_launch(void* const* d_in, const int* in_sizes, int n_in,
                              void* d_out, int out_size, void* d_ws, size_t ws_size,
                              hipStream_t stream) {
    const float* h   = (const float*)d_in[0];
    const int*   src = (const int*)d_in[1];
    const int*   dst = (const int*)d_in[2];
    const float* W1  = (const float*)d_in[3];
    const float* b1  = (const float*)d_in[4];
    const float* W2  = (const float*)d_in[5];
    const float* b2  = (const float*)d_in[6];
    const float* eps = (const float*)d_in[7];
    float* out = (float*)d_out;

    char* ws = (char*)d_ws;
    float* z    = (float*)ws;                                // 25.6 MB
    float* h2   = (float*)(ws + (size_t)26 * 1024 * 1024);   // 25.6 MB
    short* Wswz = (short*)(ws + (size_t)52 * 1024 * 1024);   // 196 KB
    char*  p    = ws + (size_t)53 * 1024 * 1024;
    int* off    = (int*)p;                 p += (size_t)(N_NODES + 1) * 4;
    int* cursor = (int*)p;                 p += (size_t)N_NODES * 4;
    int* bsum   = (int*)p;                 p += 256 * 4;
    int* esrc   = (int*)p;                 // 3.2 MB

    const int eb = (N_EDGES + 255) / 256;

    wconv<<<48, 256, 0, stream>>>(W1, W2, Wswz);
    zero_off<<<SCAN_NB, 256, 0, stream>>>(off);
    hist<<<eb, 256, 0, stream>>>(dst, off);
    scan_block<<<SCAN_NB, 256, 0, stream>>>(off, bsum);
    scan_bsum<<<1, 256, 0, stream>>>(bsum);
    scan_add<<<SCAN_NB, 256, 0, stream>>>(off, bsum, cursor);
    fill<<<eb, 256, 0, stream>>>(src, dst, cursor, esrc);

    const float* hin[3] = {h, out, h2};
    float*      hout[3] = {out, h2, out};
    const int ag_blocks = (N_NODES * 64 + 255) / 256;
    const int mm_blocks = (N_NODES + 63) / 64;

    for (int l = 0; l < NLAYER; ++l) {
        aggregate<<<ag_blocks, 256, 0, stream>>>(hin[l], off, esrc, z, eps, l);
        mlp<<<mm_blocks, 256, 0, stream>>>(z, Wswz + (size_t)l * 2 * 16384,
                                           b1 + (size_t)l * D, b2 + (size_t)l * D, hout[l]);
    }
}

// Round 3
// 258.248 us; speedup vs baseline: 15.9577x; 1.3893x over previous
//
#include <hip/hip_runtime.h>
#include <hip/hip_bf16.h>
#include <stdint.h>

#define N_NODES 50000
#define N_EDGES 800000
#define D 128
#define NLAYER 3
#define SCAN_NB ((N_NODES + 255) / 256)   // 196

typedef __attribute__((ext_vector_type(8))) short bf16x8;
typedef __attribute__((ext_vector_type(4))) float f32x4;

__device__ __forceinline__ short f2bf(float f) {
    union { float f; uint32_t u; } v; v.f = f;
    uint32_t u = v.u;
    uint32_t r = u + 0x7fffu + ((u >> 16) & 1u);   // round-to-nearest-even
    return (short)(r >> 16);
}
__device__ __forceinline__ float bf2f(short s) {
    union { uint32_t u; float f; } v;
    v.u = ((uint32_t)(uint16_t)s) << 16;
    return v.f;
}

// ---------------------------------------------------------------------------
// Weight conversion: bf16, B-fragment-swizzled (one 16B load per lane-frag).
// ---------------------------------------------------------------------------
__global__ void wconv(const float* __restrict__ W1, const float* __restrict__ W2,
                      short* __restrict__ Wswz) {
    int t = blockIdx.x * blockDim.x + threadIdx.x;   // (l,mat,ks,nt,lane)
    if (t >= NLAYER * 2 * 4 * 8 * 64) return;
    int lane = t & 63;
    int nt   = (t >> 6) & 7;
    int ks   = (t >> 9) & 3;
    int mat  = (t >> 11) & 1;
    int l    = t >> 12;
    const float* W = (mat == 0 ? W1 : W2) + (size_t)l * D * D;
    int n = nt * 16 + (lane & 15);
    short* outp = Wswz + (size_t)t * 8;
#pragma unroll
    for (int j = 0; j < 8; ++j) {
        int k = ks * 32 + (lane >> 4) * 8 + j;
        outp[j] = f2bf(W[k * D + n]);
    }
}

// h (f32) -> hbf (bf16)
__global__ void h2bf(const float* __restrict__ h, short* __restrict__ hbf) {
    int t = blockIdx.x * blockDim.x + threadIdx.x;
    if (t >= N_NODES * D / 8) return;
    f32x4 a = ((const f32x4*)h)[2 * t];
    f32x4 b = ((const f32x4*)h)[2 * t + 1];
    bf16x8 o;
    o[0] = f2bf(a.x); o[1] = f2bf(a.y); o[2] = f2bf(a.z); o[3] = f2bf(a.w);
    o[4] = f2bf(b.x); o[5] = f2bf(b.y); o[6] = f2bf(b.z); o[7] = f2bf(b.w);
    ((bf16x8*)hbf)[t] = o;
}

// ---------------------------------------------------------------------------
// CSR build: zero -> histogram -> 3-kernel exclusive scan -> fill
// ---------------------------------------------------------------------------
__global__ void zero_off(int* __restrict__ off) {
    int i = blockIdx.x * blockDim.x + threadIdx.x;
    if (i <= N_NODES) off[i] = 0;
}

__global__ void hist(const int* __restrict__ dst, int* __restrict__ off) {
    int e = blockIdx.x * blockDim.x + threadIdx.x;
    if (e < N_EDGES) atomicAdd(&off[dst[e]], 1);
}

__global__ void scan_block(int* __restrict__ off, int* __restrict__ bsum) {
    __shared__ int tmp[256];
    int i = blockIdx.x * 256 + threadIdx.x;
    int v = (i < N_NODES) ? off[i] : 0;
    tmp[threadIdx.x] = v;
    __syncthreads();
#pragma unroll
    for (int s = 1; s < 256; s <<= 1) {
        int t = (threadIdx.x >= s) ? tmp[threadIdx.x - s] : 0;
        __syncthreads();
        tmp[threadIdx.x] += t;
        __syncthreads();
    }
    if (i < N_NODES) off[i] = tmp[threadIdx.x] - v;      // exclusive within block
    if (threadIdx.x == 255) bsum[blockIdx.x] = tmp[255]; // block total
}

__global__ void scan_bsum(int* __restrict__ bsum) {
    __shared__ int tmp[256];
    int v = (threadIdx.x < SCAN_NB) ? bsum[threadIdx.x] : 0;
    tmp[threadIdx.x] = v;
    __syncthreads();
#pragma unroll
    for (int s = 1; s < 256; s <<= 1) {
        int t = (threadIdx.x >= s) ? tmp[threadIdx.x - s] : 0;
        __syncthreads();
        tmp[threadIdx.x] += t;
        __syncthreads();
    }
    if (threadIdx.x < SCAN_NB) bsum[threadIdx.x] = tmp[threadIdx.x] - v; // exclusive
}

__global__ void scan_add(int* __restrict__ off, const int* __restrict__ bsum,
                         int* __restrict__ cursor) {
    int i = blockIdx.x * 256 + threadIdx.x;
    if (i < N_NODES) {
        int o = off[i] + bsum[blockIdx.x];
        off[i] = o;
        cursor[i] = o;
    }
    if (i == 0) off[N_NODES] = N_EDGES;
}

__global__ void fill(const int* __restrict__ src, const int* __restrict__ dst,
                     int* __restrict__ cursor, int* __restrict__ esrc) {
    int e = blockIdx.x * blockDim.x + threadIdx.x;
    if (e < N_EDGES) {
        int p = atomicAdd(&cursor[dst[e]], 1);
        esrc[p] = src[e];
    }
}

// ---------------------------------------------------------------------------
// Pull aggregation, bf16 rows. One wave per node; lane = (edge-slot g, col c).
// 4 edges in flight per iteration, each a 256B coalesced row read; cross-slot
// reduce via shfl_xor. z written bf16.
// ---------------------------------------------------------------------------
__global__ __launch_bounds__(256) void aggregate(const short* __restrict__ hbf,
                                                 const int* __restrict__ off,
                                                 const int* __restrict__ esrc,
                                                 short* __restrict__ zbf,
                                                 const float* __restrict__ eps, int l) {
    int gw = (blockIdx.x * 256 + threadIdx.x) >> 6;   // node
    int lane = threadIdx.x & 63;
    if (gw >= N_NODES) return;
    const int g = lane >> 4;     // edge slot 0..3
    const int c = lane & 15;     // col group (8 bf16 each)

    float acc[8];
#pragma unroll
    for (int i = 0; i < 8; ++i) acc[i] = 0.0f;

    const int start = off[gw], end = off[gw + 1];
    int j = start + g;
    for (; j + 4 < end; j += 8) {
        int u0 = esrc[j];
        int u1 = esrc[j + 4];
        bf16x8 r0 = *(const bf16x8*)(hbf + (size_t)u0 * D + c * 8);
        bf16x8 r1 = *(const bf16x8*)(hbf + (size_t)u1 * D + c * 8);
#pragma unroll
        for (int i = 0; i < 8; ++i) acc[i] += bf2f(r0[i]) + bf2f(r1[i]);
    }
    if (j < end) {
        int u0 = esrc[j];
        bf16x8 r0 = *(const bf16x8*)(hbf + (size_t)u0 * D + c * 8);
#pragma unroll
        for (int i = 0; i < 8; ++i) acc[i] += bf2f(r0[i]);
    }

    // reduce across the 4 edge slots (lanes l, l+16, l+32, l+48)
#pragma unroll
    for (int i = 0; i < 8; ++i) {
        acc[i] += __shfl_xor(acc[i], 16, 64);
        acc[i] += __shfl_xor(acc[i], 32, 64);
    }

    // self term + store (slot 0 lanes only: 16 lanes x 16B = full 256B row)
    const float s = 1.0f + eps[l];
    bf16x8 sv = *(const bf16x8*)(hbf + (size_t)gw * D + c * 8);
    bf16x8 o;
#pragma unroll
    for (int i = 0; i < 8; ++i) o[i] = f2bf(acc[i] + s * bf2f(sv[i]));
    if (g == 0) *(bf16x8*)(zbf + (size_t)gw * D + c * 8) = o;
}

// ---------------------------------------------------------------------------
// Fused MLP: out = relu(z @ W1 + b1) @ W2 + b2.  z in bf16 (direct A-frags).
// ---------------------------------------------------------------------------
__global__ __launch_bounds__(256) void mlp(const short* __restrict__ zbf,
                                           const short* __restrict__ Wl,
                                           const float* __restrict__ b1,
                                           const float* __restrict__ b2,
                                           float* __restrict__ outf,
                                           short* __restrict__ outbf, int last) {
    __shared__ short hlds[4][16 * 128];
    const int lane = threadIdx.x & 63;
    const int wid  = threadIdx.x >> 6;
    const int rowbase = (blockIdx.x * 4 + wid) * 16;
    if (rowbase >= N_NODES) return;           // wave-uniform exit; no __syncthreads used
    const int r0 = lane & 15;
    const int kh = lane >> 4;
    const int row = rowbase + r0;
    const int zrow = (row < N_NODES) ? row : (N_NODES - 1);
    short* hl = hlds[wid];

    f32x4 acc[8];
#pragma unroll
    for (int nt = 0; nt < 8; ++nt) acc[nt] = (f32x4)(0.0f);

#pragma unroll
    for (int ks = 0; ks < 4; ++ks) {
        bf16x8 af = *(const bf16x8*)(zbf + (size_t)zrow * D + ks * 32 + kh * 8);
        const short* wp = Wl + ((size_t)(ks * 8) * 64 + lane) * 8;
#pragma unroll
        for (int nt = 0; nt < 8; ++nt) {
            bf16x8 bf = *(const bf16x8*)(wp + (size_t)nt * 64 * 8);
            acc[nt] = __builtin_amdgcn_mfma_f32_16x16x32_bf16(af, bf, acc[nt], 0, 0, 0);
        }
    }

#pragma unroll
    for (int nt = 0; nt < 8; ++nt) {
        int col = nt * 16 + r0;
        float bias = b1[col];
#pragma unroll
        for (int r = 0; r < 4; ++r) {
            int hrow = kh * 4 + r;
            float v = fmaxf(acc[nt][r] + bias, 0.0f);
            hl[hrow * 128 + (col ^ ((hrow & 7) << 3))] = f2bf(v);
        }
    }
    asm volatile("s_waitcnt lgkmcnt(0)" ::: "memory");

    f32x4 acc2[8];
#pragma unroll
    for (int nt = 0; nt < 8; ++nt) acc2[nt] = (f32x4)(0.0f);

    const short* W2p = Wl + 4 * 8 * 64 * 8;
#pragma unroll
    for (int ks = 0; ks < 4; ++ks) {
        int c0 = ks * 32 + kh * 8;
        bf16x8 af = *(const bf16x8*)&hl[r0 * 128 + (c0 ^ ((r0 & 7) << 3))];
        const short* wp = W2p + ((size_t)(ks * 8) * 64 + lane) * 8;
#pragma unroll
        for (int nt = 0; nt < 8; ++nt) {
            bf16x8 bf = *(const bf16x8*)(wp + (size_t)nt * 64 * 8);
            acc2[nt] = __builtin_amdgcn_mfma_f32_16x16x32_bf16(af, bf, acc2[nt], 0, 0, 0);
        }
    }

#pragma unroll
    for (int nt = 0; nt < 8; ++nt) {
        int col = nt * 16 + r0;
        float bias = b2[col];
#pragma unroll
        for (int r = 0; r < 4; ++r) {
            int orow = rowbase + kh * 4 + r;
            if (orow < N_NODES) {
                float v = acc2[nt][r] + bias;
                if (last) outf[(size_t)orow * D + col] = v;
                else      outbf[(size_t)orow * D + col] = f2bf(v);
            }
        }
    }
}

extern "C" void kernel_launch(void* const* d_in, const int* in_sizes, int n_in,
                              void* d_out, int out_size, void* d_ws, size_t ws_size,
                              hipStream_t stream) {
    const float* h   = (const float*)d_in[0];
    const int*   src = (const int*)d_in[1];
    const int*   dst = (const int*)d_in[2];
    const float* W1  = (const float*)d_in[3];
    const float* b1  = (const float*)d_in[4];
    const float* W2  = (const float*)d_in[5];
    const float* b2  = (const float*)d_in[6];
    const float* eps = (const float*)d_in[7];
    float* out = (float*)d_out;

    char* ws = (char*)d_ws;
    const size_t MB = 1024 * 1024;
    short* hbfA = (short*)ws;                        // 12.8 MB
    short* hbfB = (short*)(ws + 13 * MB);            // 12.8 MB
    short* zbf  = (short*)(ws + 26 * MB);            // 12.8 MB
    short* Wswz = (short*)(ws + 39 * MB);            // 196 KB
    char*  p    = ws + 40 * MB;
    int* off    = (int*)p;                 p += (size_t)(N_NODES + 1) * 4;
    int* cursor = (int*)p;                 p += (size_t)N_NODES * 4;
    int* bsum   = (int*)p;                 p += 256 * 4;
    int* esrc   = (int*)p;                 // 3.2 MB

    const int eb = (N_EDGES + 255) / 256;

    wconv<<<48, 256, 0, stream>>>(W1, W2, Wswz);
    h2bf<<<(N_NODES * D / 8 + 255) / 256, 256, 0, stream>>>(h, hbfA);
    zero_off<<<SCAN_NB, 256, 0, stream>>>(off);
    hist<<<eb, 256, 0, stream>>>(dst, off);
    scan_block<<<SCAN_NB, 256, 0, stream>>>(off, bsum);
    scan_bsum<<<1, 256, 0, stream>>>(bsum);
    scan_add<<<SCAN_NB, 256, 0, stream>>>(off, bsum, cursor);
    fill<<<eb, 256, 0, stream>>>(src, dst, cursor, esrc);

    const short* hin[3] = {hbfA, hbfB, hbfA};
    short*      houtbf[3] = {hbfB, hbfA, nullptr};
    const int ag_blocks = (N_NODES * 64 + 255) / 256;
    const int mm_blocks = (N_NODES + 63) / 64;

    for (int l = 0; l < NLAYER; ++l) {
        aggregate<<<ag_blocks, 256, 0, stream>>>(hin[l], off, esrc, zbf, eps, l);
        mlp<<<mm_blocks, 256, 0, stream>>>(zbf, Wswz + (size_t)l * 2 * 16384,
                                           b1 + (size_t)l * D, b2 + (size_t)l * D,
                                           out, houtbf[l], l == NLAYER - 1 ? 1 : 0);
    }
}

// Round 4
// 233.393 us; speedup vs baseline: 17.6572x; 1.1065x over previous
//
#include <hip/hip_runtime.h>
#include <hip/hip_bf16.h>
#include <stdint.h>

#define N_NODES 50000
#define N_EDGES 800000
#define D 128
#define NLAYER 3
#define SCAN_NB ((N_NODES + 255) / 256)   // 196

typedef __attribute__((ext_vector_type(8))) short bf16x8;
typedef __attribute__((ext_vector_type(4))) float f32x4;

__device__ __forceinline__ short f2bf(float f) {
    union { float f; uint32_t u; } v; v.f = f;
    uint32_t u = v.u;
    uint32_t r = u + 0x7fffu + ((u >> 16) & 1u);   // round-to-nearest-even
    return (short)(r >> 16);
}
__device__ __forceinline__ float bf2f(short s) {
    union { uint32_t u; float f; } v;
    v.u = ((uint32_t)(uint16_t)s) << 16;
    return v.f;
}

// ---------------------------------------------------------------------------
// Weight conversion: bf16, B-fragment-swizzled (one 16B load per lane-frag).
// ---------------------------------------------------------------------------
__global__ void wconv(const float* __restrict__ W1, const float* __restrict__ W2,
                      short* __restrict__ Wswz) {
    int t = blockIdx.x * blockDim.x + threadIdx.x;   // (l,mat,ks,nt,lane)
    if (t >= NLAYER * 2 * 4 * 8 * 64) return;
    int lane = t & 63;
    int nt   = (t >> 6) & 7;
    int ks   = (t >> 9) & 3;
    int mat  = (t >> 11) & 1;
    int l    = t >> 12;
    const float* W = (mat == 0 ? W1 : W2) + (size_t)l * D * D;
    int n = nt * 16 + (lane & 15);
    short* outp = Wswz + (size_t)t * 8;
#pragma unroll
    for (int j = 0; j < 8; ++j) {
        int k = ks * 32 + (lane >> 4) * 8 + j;
        outp[j] = f2bf(W[k * D + n]);
    }
}

// h (f32) -> hbf (bf16)
__global__ void h2bf(const float* __restrict__ h, short* __restrict__ hbf) {
    int t = blockIdx.x * blockDim.x + threadIdx.x;
    if (t >= N_NODES * D / 8) return;
    f32x4 a = ((const f32x4*)h)[2 * t];
    f32x4 b = ((const f32x4*)h)[2 * t + 1];
    bf16x8 o;
    o[0] = f2bf(a.x); o[1] = f2bf(a.y); o[2] = f2bf(a.z); o[3] = f2bf(a.w);
    o[4] = f2bf(b.x); o[5] = f2bf(b.y); o[6] = f2bf(b.z); o[7] = f2bf(b.w);
    ((bf16x8*)hbf)[t] = o;
}

// ---------------------------------------------------------------------------
// CSR build: zero -> histogram -> 3-kernel exclusive scan -> fill
// ---------------------------------------------------------------------------
__global__ void zero_off(int* __restrict__ off) {
    int i = blockIdx.x * blockDim.x + threadIdx.x;
    if (i <= N_NODES) off[i] = 0;
}

__global__ void hist(const int* __restrict__ dst, int* __restrict__ off) {
    int e = blockIdx.x * blockDim.x + threadIdx.x;
    if (e < N_EDGES) atomicAdd(&off[dst[e]], 1);
}

__global__ void scan_block(int* __restrict__ off, int* __restrict__ bsum) {
    __shared__ int tmp[256];
    int i = blockIdx.x * 256 + threadIdx.x;
    int v = (i < N_NODES) ? off[i] : 0;
    tmp[threadIdx.x] = v;
    __syncthreads();
#pragma unroll
    for (int s = 1; s < 256; s <<= 1) {
        int t = (threadIdx.x >= s) ? tmp[threadIdx.x - s] : 0;
        __syncthreads();
        tmp[threadIdx.x] += t;
        __syncthreads();
    }
    if (i < N_NODES) off[i] = tmp[threadIdx.x] - v;      // exclusive within block
    if (threadIdx.x == 255) bsum[blockIdx.x] = tmp[255]; // block total
}

__global__ void scan_bsum(int* __restrict__ bsum) {
    __shared__ int tmp[256];
    int v = (threadIdx.x < SCAN_NB) ? bsum[threadIdx.x] : 0;
    tmp[threadIdx.x] = v;
    __syncthreads();
#pragma unroll
    for (int s = 1; s < 256; s <<= 1) {
        int t = (threadIdx.x >= s) ? tmp[threadIdx.x - s] : 0;
        __syncthreads();
        tmp[threadIdx.x] += t;
        __syncthreads();
    }
    if (threadIdx.x < SCAN_NB) bsum[threadIdx.x] = tmp[threadIdx.x] - v; // exclusive
}

__global__ void scan_add(int* __restrict__ off, const int* __restrict__ bsum,
                         int* __restrict__ cursor) {
    int i = blockIdx.x * 256 + threadIdx.x;
    if (i < N_NODES) {
        int o = off[i] + bsum[blockIdx.x];
        off[i] = o;
        cursor[i] = o;
    }
    if (i == 0) off[N_NODES] = N_EDGES;
}

__global__ void fill(const int* __restrict__ src, const int* __restrict__ dst,
                     int* __restrict__ cursor, int* __restrict__ esrc) {
    int e = blockIdx.x * blockDim.x + threadIdx.x;
    if (e < N_EDGES) {
        int p = atomicAdd(&cursor[dst[e]], 1);
        esrc[p] = src[e];
    }
}

// ---------------------------------------------------------------------------
// Fused GIN layer: block = 16 nodes (grid is exactly N_NODES/16), 4 waves.
// Phase A: each wave aggregates 4 nodes (slot-parallel gather, 16 rows in
//          flight) into swizzled LDS z-tile.
// Phase B: cooperative 16x128 @ 128x128 MFMA x2 with ReLU, hid via LDS.
// ---------------------------------------------------------------------------
__global__ __launch_bounds__(256) void gin_layer(const short* __restrict__ hbf,
                                                 const int* __restrict__ off,
                                                 const int* __restrict__ esrc,
                                                 const short* __restrict__ Wl,
                                                 const float* __restrict__ b1,
                                                 const float* __restrict__ b2,
                                                 const float* __restrict__ eps, int l,
                                                 float* __restrict__ outf,
                                                 short* __restrict__ outbf, int last) {
    __shared__ short zl[16 * 128];
    __shared__ short hl[16 * 128];
    const int lane = threadIdx.x & 63;
    const int wid  = threadIdx.x >> 6;
    const int rowbase = blockIdx.x * 16;
    const int g = lane >> 4;     // edge slot 0..3
    const int c = lane & 15;     // col granule (8 bf16 = 16B)
    const float s = 1.0f + eps[l];

    // ---- Phase A: aggregation, wave wid owns LDS rows wid*4 .. wid*4+3 ----
    for (int i = 0; i < 4; ++i) {
        const int lrow = wid * 4 + i;
        const int node = rowbase + lrow;
        float acc[8];
#pragma unroll
        for (int k = 0; k < 8; ++k) acc[k] = 0.0f;
        const int start = off[node], end = off[node + 1];
        int j = start + g;
        for (; j + 12 < end; j += 16) {            // 4 rows in flight per slot
            int u0 = esrc[j], u1 = esrc[j + 4], u2 = esrc[j + 8], u3 = esrc[j + 12];
            bf16x8 r0 = *(const bf16x8*)(hbf + (size_t)u0 * D + c * 8);
            bf16x8 r1 = *(const bf16x8*)(hbf + (size_t)u1 * D + c * 8);
            bf16x8 r2 = *(const bf16x8*)(hbf + (size_t)u2 * D + c * 8);
            bf16x8 r3 = *(const bf16x8*)(hbf + (size_t)u3 * D + c * 8);
#pragma unroll
            for (int k = 0; k < 8; ++k)
                acc[k] += (bf2f(r0[k]) + bf2f(r1[k])) + (bf2f(r2[k]) + bf2f(r3[k]));
        }
        for (; j < end; j += 4) {
            int u0 = esrc[j];
            bf16x8 r0 = *(const bf16x8*)(hbf + (size_t)u0 * D + c * 8);
#pragma unroll
            for (int k = 0; k < 8; ++k) acc[k] += bf2f(r0[k]);
        }
        // reduce across the 4 edge slots
#pragma unroll
        for (int k = 0; k < 8; ++k) {
            acc[k] += __shfl_xor(acc[k], 16, 64);
            acc[k] += __shfl_xor(acc[k], 32, 64);
        }
        // self term + store to swizzled LDS (slot 0 = 16 lanes x 16B = row)
        bf16x8 sv = *(const bf16x8*)(hbf + (size_t)node * D + c * 8);
        if (g == 0) {
            bf16x8 o;
#pragma unroll
            for (int k = 0; k < 8; ++k) o[k] = f2bf(acc[k] + s * bf2f(sv[k]));
            *(bf16x8*)&zl[lrow * 128 + ((c ^ (lrow & 7)) * 8)] = o;
        }
    }
    __syncthreads();

    // ---- Phase B: MLP. Wave wid owns n-tiles {2*wid, 2*wid+1}. ----
    const int r0 = lane & 15;
    const int kh = lane >> 4;

    f32x4 acc1[2];
    acc1[0] = (f32x4)(0.0f); acc1[1] = (f32x4)(0.0f);
#pragma unroll
    for (int ks = 0; ks < 4; ++ks) {
        int gidx = ks * 4 + kh;
        bf16x8 af = *(const bf16x8*)&zl[r0 * 128 + ((gidx ^ (r0 & 7)) * 8)];
#pragma unroll
        for (int t = 0; t < 2; ++t) {
            int nt = wid * 2 + t;
            bf16x8 bf = *(const bf16x8*)(Wl + ((size_t)(ks * 8 + nt) * 64 + lane) * 8);
            acc1[t] = __builtin_amdgcn_mfma_f32_16x16x32_bf16(af, bf, acc1[t], 0, 0, 0);
        }
    }
#pragma unroll
    for (int t = 0; t < 2; ++t) {
        int col = (wid * 2 + t) * 16 + r0;
        float bias = b1[col];
#pragma unroll
        for (int r = 0; r < 4; ++r) {
            int hrow = kh * 4 + r;
            float v = fmaxf(acc1[t][r] + bias, 0.0f);
            hl[hrow * 128 + (col ^ ((hrow & 7) << 3))] = f2bf(v);
        }
    }
    __syncthreads();

    f32x4 acc2[2];
    acc2[0] = (f32x4)(0.0f); acc2[1] = (f32x4)(0.0f);
    const short* W2p = Wl + 4 * 8 * 64 * 8;
#pragma unroll
    for (int ks = 0; ks < 4; ++ks) {
        int c0 = ks * 32 + kh * 8;
        bf16x8 af = *(const bf16x8*)&hl[r0 * 128 + (c0 ^ ((r0 & 7) << 3))];
#pragma unroll
        for (int t = 0; t < 2; ++t) {
            int nt = wid * 2 + t;
            bf16x8 bf = *(const bf16x8*)(W2p + ((size_t)(ks * 8 + nt) * 64 + lane) * 8);
            acc2[t] = __builtin_amdgcn_mfma_f32_16x16x32_bf16(af, bf, acc2[t], 0, 0, 0);
        }
    }
#pragma unroll
    for (int t = 0; t < 2; ++t) {
        int col = (wid * 2 + t) * 16 + r0;
        float bias = b2[col];
#pragma unroll
        for (int r = 0; r < 4; ++r) {
            int orow = rowbase + kh * 4 + r;   // always < N_NODES (exact grid)
            float v = acc2[t][r] + bias;
            if (last) outf[(size_t)orow * D + col] = v;
            else      outbf[(size_t)orow * D + col] = f2bf(v);
        }
    }
}

extern "C" void kernel_launch(void* const* d_in, const int* in_sizes, int n_in,
                              void* d_out, int out_size, void* d_ws, size_t ws_size,
                              hipStream_t stream) {
    const float* h   = (const float*)d_in[0];
    const int*   src = (const int*)d_in[1];
    const int*   dst = (const int*)d_in[2];
    const float* W1  = (const float*)d_in[3];
    const float* b1  = (const float*)d_in[4];
    const float* W2  = (const float*)d_in[5];
    const float* b2  = (const float*)d_in[6];
    const float* eps = (const float*)d_in[7];
    float* out = (float*)d_out;

    char* ws = (char*)d_ws;
    const size_t MB = 1024 * 1024;
    short* hbfA = (short*)ws;                        // 12.8 MB
    short* hbfB = (short*)(ws + 13 * MB);            // 12.8 MB
    short* Wswz = (short*)(ws + 26 * MB);            // 196 KB
    char*  p    = ws + 27 * MB;
    int* off    = (int*)p;                 p += (size_t)(N_NODES + 1) * 4;
    int* cursor = (int*)p;                 p += (size_t)N_NODES * 4;
    int* bsum   = (int*)p;                 p += 256 * 4;
    int* esrc   = (int*)p;                 // 3.2 MB

    const int eb = (N_EDGES + 255) / 256;

    wconv<<<48, 256, 0, stream>>>(W1, W2, Wswz);
    h2bf<<<(N_NODES * D / 8 + 255) / 256, 256, 0, stream>>>(h, hbfA);
    zero_off<<<SCAN_NB, 256, 0, stream>>>(off);
    hist<<<eb, 256, 0, stream>>>(dst, off);
    scan_block<<<SCAN_NB, 256, 0, stream>>>(off, bsum);
    scan_bsum<<<1, 256, 0, stream>>>(bsum);
    scan_add<<<SCAN_NB, 256, 0, stream>>>(off, bsum, cursor);
    fill<<<eb, 256, 0, stream>>>(src, dst, cursor, esrc);

    const short* hin[3]  = {hbfA, hbfB, hbfA};
    short*      houtbf[3] = {hbfB, hbfA, nullptr};
    const int layer_blocks = N_NODES / 16;           // 3125, exact

    for (int l = 0; l < NLAYER; ++l) {
        gin_layer<<<layer_blocks, 256, 0, stream>>>(hin[l], off, esrc,
                                                    Wswz + (size_t)l * 2 * 16384,
                                                    b1 + (size_t)l * D, b2 + (size_t)l * D,
                                                    eps, l, out, houtbf[l],
                                                    l == NLAYER - 1 ? 1 : 0);
    }
}

// Round 5
// 179.047 us; speedup vs baseline: 23.0166x; 1.3035x over previous
//
#include <hip/hip_runtime.h>
#include <hip/hip_bf16.h>
#include <stdint.h>

#define N_NODES 50000
#define N_EDGES 800000
#define D 128
#define NLAYER 3

#define BKT_SHIFT 7
#define NBKT ((N_NODES + 127) / 128)          // 391 buckets of 128 nodes
#define EPB 4096                               // edges per block, bucket passes
#define BKT_BLOCKS ((N_EDGES + EPB - 1) / EPB) // 196
#define CAP 3072                               // LDS edge cap per bucket (avg 2046)

typedef __attribute__((ext_vector_type(8))) short bf16x8;
typedef __attribute__((ext_vector_type(4))) float f32x4;

__device__ __forceinline__ short f2bf(float f) {
    union { float f; uint32_t u; } v; v.f = f;
    uint32_t u = v.u;
    uint32_t r = u + 0x7fffu + ((u >> 16) & 1u);   // round-to-nearest-even
    return (short)(r >> 16);
}
__device__ __forceinline__ float bf2f(short s) {
    union { uint32_t u; float f; } v;
    v.u = ((uint32_t)(uint16_t)s) << 16;
    return v.f;
}

// ---------------------------------------------------------------------------
// Weight conversion: bf16, B-fragment-swizzled (one 16B load per lane-frag).
// ---------------------------------------------------------------------------
__global__ void wconv(const float* __restrict__ W1, const float* __restrict__ W2,
                      short* __restrict__ Wswz) {
    int t = blockIdx.x * blockDim.x + threadIdx.x;   // (l,mat,ks,nt,lane)
    if (t >= NLAYER * 2 * 4 * 8 * 64) return;
    int lane = t & 63;
    int nt   = (t >> 6) & 7;
    int ks   = (t >> 9) & 3;
    int mat  = (t >> 11) & 1;
    int l    = t >> 12;
    const float* W = (mat == 0 ? W1 : W2) + (size_t)l * D * D;
    int n = nt * 16 + (lane & 15);
    short* outp = Wswz + (size_t)t * 8;
#pragma unroll
    for (int j = 0; j < 8; ++j) {
        int k = ks * 32 + (lane >> 4) * 8 + j;
        outp[j] = f2bf(W[k * D + n]);
    }
}

// h (f32) -> hbf (bf16)
__global__ void h2bf(const float* __restrict__ h, short* __restrict__ hbf) {
    int t = blockIdx.x * blockDim.x + threadIdx.x;
    if (t >= N_NODES * D / 8) return;
    f32x4 a = ((const f32x4*)h)[2 * t];
    f32x4 b = ((const f32x4*)h)[2 * t + 1];
    bf16x8 o;
    o[0] = f2bf(a.x); o[1] = f2bf(a.y); o[2] = f2bf(a.z); o[3] = f2bf(a.w);
    o[4] = f2bf(b.x); o[5] = f2bf(b.y); o[6] = f2bf(b.z); o[7] = f2bf(b.w);
    ((bf16x8*)hbf)[t] = o;
}

__global__ void zero_int(int* __restrict__ p, int n) {
    int i = blockIdx.x * blockDim.x + threadIdx.x;
    if (i < n) p[i] = 0;
}

// ---------------------------------------------------------------------------
// CSR build, two-level bucket counting sort (line-dense writes):
//   bucket_hist -> bucket_scan -> bucket_scatter (pairs) -> csr_build
// ---------------------------------------------------------------------------
__global__ __launch_bounds__(256) void bucket_hist(const int* __restrict__ dst,
                                                   int* __restrict__ bcnt) {
    __shared__ int hcnt[NBKT];
    for (int i = threadIdx.x; i < NBKT; i += 256) hcnt[i] = 0;
    __syncthreads();
    int base = blockIdx.x * EPB;
    int end = base + EPB; if (end > N_EDGES) end = N_EDGES;
    for (int e = base + threadIdx.x; e < end; e += 256)
        atomicAdd(&hcnt[dst[e] >> BKT_SHIFT], 1);
    __syncthreads();
    for (int i = threadIdx.x; i < NBKT; i += 256)
        if (hcnt[i]) atomicAdd(&bcnt[i], hcnt[i]);
}

__global__ __launch_bounds__(512) void bucket_scan(const int* __restrict__ bcnt,
                                                   int* __restrict__ bbase,
                                                   int* __restrict__ bcur) {
    __shared__ int tmp[512];
    int v = (threadIdx.x < NBKT) ? bcnt[threadIdx.x] : 0;
    tmp[threadIdx.x] = v;
    __syncthreads();
#pragma unroll
    for (int s = 1; s < 512; s <<= 1) {
        int t = (threadIdx.x >= s) ? tmp[threadIdx.x - s] : 0;
        __syncthreads();
        tmp[threadIdx.x] += t;
        __syncthreads();
    }
    if (threadIdx.x < NBKT) {
        int b = tmp[threadIdx.x] - v;       // exclusive
        bbase[threadIdx.x] = b;
        bcur[threadIdx.x]  = b;
    }
    if (threadIdx.x == 0) bbase[NBKT] = N_EDGES;
}

__global__ __launch_bounds__(256) void bucket_scatter(const int* __restrict__ src,
                                                      const int* __restrict__ dst,
                                                      int* __restrict__ bcur,
                                                      int2* __restrict__ pairs) {
    __shared__ int hcnt[NBKT];
    __shared__ int hbase[NBKT];
    for (int i = threadIdx.x; i < NBKT; i += 256) hcnt[i] = 0;
    __syncthreads();
    int base = blockIdx.x * EPB;
    int end = base + EPB; if (end > N_EDGES) end = N_EDGES;
    for (int e = base + threadIdx.x; e < end; e += 256)
        atomicAdd(&hcnt[dst[e] >> BKT_SHIFT], 1);
    __syncthreads();
    for (int i = threadIdx.x; i < NBKT; i += 256) {
        int c = hcnt[i];
        hbase[i] = c ? atomicAdd(&bcur[i], c) : 0;
        hcnt[i] = 0;                         // reuse as local rank cursor
    }
    __syncthreads();
    for (int e = base + threadIdx.x; e < end; e += 256) {
        int d = dst[e];
        int b = d >> BKT_SHIFT;
        int r = atomicAdd(&hcnt[b], 1);
        pairs[(size_t)hbase[b] + r] = make_int2(src[e], d);
    }
}

// One block per bucket: node histogram -> scan -> off[], rank edges into LDS,
// stream esrc out sequentially (full-line writes).
__global__ __launch_bounds__(256) void csr_build(const int2* __restrict__ pairs,
                                                 const int* __restrict__ bbase,
                                                 int* __restrict__ off,
                                                 int* __restrict__ esrc) {
    __shared__ int ncnt[128];
    __shared__ int noff[129];
    __shared__ int esl[CAP];
    const int b = blockIdx.x;
    const int lo = bbase[b], hi = bbase[b + 1];
    const int n0 = b << BKT_SHIFT;
    const int nN = (N_NODES - n0 < 128) ? (N_NODES - n0) : 128;

    if (threadIdx.x < 128) ncnt[threadIdx.x] = 0;
    __syncthreads();
    for (int e = lo + threadIdx.x; e < hi; e += 256)
        atomicAdd(&ncnt[pairs[e].y & 127], 1);
    __syncthreads();

    // exclusive scan of ncnt[0..127] into noff[0..128]
    if (threadIdx.x < 128) noff[threadIdx.x + 1] = ncnt[threadIdx.x];
    if (threadIdx.x == 0) noff[0] = 0;
    __syncthreads();
#pragma unroll
    for (int s = 1; s < 256; s <<= 1) {
        int t = (threadIdx.x < 129 && threadIdx.x >= s) ? noff[threadIdx.x - s] : 0;
        __syncthreads();
        if (threadIdx.x < 129) noff[threadIdx.x] += t;
        __syncthreads();
    }

    if (threadIdx.x < nN) off[n0 + threadIdx.x] = lo + noff[threadIdx.x];
    if (b == 0 && threadIdx.x == 0) off[N_NODES] = N_EDGES;

    if (threadIdx.x < 128) ncnt[threadIdx.x] = noff[threadIdx.x];  // rank cursors
    __syncthreads();

    const int cnt = hi - lo;
    if (cnt <= CAP) {
        for (int e = lo + threadIdx.x; e < hi; e += 256) {
            int2 p = pairs[e];
            int r = atomicAdd(&ncnt[p.y & 127], 1);
            esl[r] = p.x;
        }
        __syncthreads();
        for (int i = threadIdx.x; i < cnt; i += 256) esrc[lo + i] = esl[i];
    } else {  // overflow fallback (never expected at Poisson(2048) vs CAP=3072)
        for (int e = lo + threadIdx.x; e < hi; e += 256) {
            int2 p = pairs[e];
            int r = atomicAdd(&ncnt[p.y & 127], 1);
            esrc[(size_t)lo + r] = p.x;
        }
    }
}

// ---------------------------------------------------------------------------
// Fused GIN layer: block = 16 nodes (grid exactly N_NODES/16), 4 waves.
// ---------------------------------------------------------------------------
__global__ __launch_bounds__(256) void gin_layer(const short* __restrict__ hbf,
                                                 const int* __restrict__ off,
                                                 const int* __restrict__ esrc,
                                                 const short* __restrict__ Wl,
                                                 const float* __restrict__ b1,
                                                 const float* __restrict__ b2,
                                                 const float* __restrict__ eps, int l,
                                                 float* __restrict__ outf,
                                                 short* __restrict__ outbf, int last) {
    __shared__ short zl[16 * 128];
    __shared__ short hl[16 * 128];
    const int lane = threadIdx.x & 63;
    const int wid  = threadIdx.x >> 6;
    const int rowbase = blockIdx.x * 16;
    const int g = lane >> 4;     // edge slot 0..3
    const int c = lane & 15;     // col granule (8 bf16 = 16B)
    const float s = 1.0f + eps[l];

    for (int i = 0; i < 4; ++i) {
        const int lrow = wid * 4 + i;
        const int node = rowbase + lrow;
        float acc[8];
#pragma unroll
        for (int k = 0; k < 8; ++k) acc[k] = 0.0f;
        const int start = off[node], end = off[node + 1];
        int j = start + g;
        for (; j + 12 < end; j += 16) {            // 4 rows in flight per slot
            int u0 = esrc[j], u1 = esrc[j + 4], u2 = esrc[j + 8], u3 = esrc[j + 12];
            bf16x8 r0 = *(const bf16x8*)(hbf + (size_t)u0 * D + c * 8);
            bf16x8 r1 = *(const bf16x8*)(hbf + (size_t)u1 * D + c * 8);
            bf16x8 r2 = *(const bf16x8*)(hbf + (size_t)u2 * D + c * 8);
            bf16x8 r3 = *(const bf16x8*)(hbf + (size_t)u3 * D + c * 8);
#pragma unroll
            for (int k = 0; k < 8; ++k)
                acc[k] += (bf2f(r0[k]) + bf2f(r1[k])) + (bf2f(r2[k]) + bf2f(r3[k]));
        }
        for (; j < end; j += 4) {
            int u0 = esrc[j];
            bf16x8 r0 = *(const bf16x8*)(hbf + (size_t)u0 * D + c * 8);
#pragma unroll
            for (int k = 0; k < 8; ++k) acc[k] += bf2f(r0[k]);
        }
#pragma unroll
        for (int k = 0; k < 8; ++k) {
            acc[k] += __shfl_xor(acc[k], 16, 64);
            acc[k] += __shfl_xor(acc[k], 32, 64);
        }
        bf16x8 sv = *(const bf16x8*)(hbf + (size_t)node * D + c * 8);
        if (g == 0) {
            bf16x8 o;
#pragma unroll
            for (int k = 0; k < 8; ++k) o[k] = f2bf(acc[k] + s * bf2f(sv[k]));
            *(bf16x8*)&zl[lrow * 128 + ((c ^ (lrow & 7)) * 8)] = o;
        }
    }
    __syncthreads();

    const int r0i = lane & 15;
    const int kh = lane >> 4;

    f32x4 acc1[2];
    acc1[0] = (f32x4)(0.0f); acc1[1] = (f32x4)(0.0f);
#pragma unroll
    for (int ks = 0; ks < 4; ++ks) {
        int gidx = ks * 4 + kh;
        bf16x8 af = *(const bf16x8*)&zl[r0i * 128 + ((gidx ^ (r0i & 7)) * 8)];
#pragma unroll
        for (int t = 0; t < 2; ++t) {
            int nt = wid * 2 + t;
            bf16x8 bf = *(const bf16x8*)(Wl + ((size_t)(ks * 8 + nt) * 64 + lane) * 8);
            acc1[t] = __builtin_amdgcn_mfma_f32_16x16x32_bf16(af, bf, acc1[t], 0, 0, 0);
        }
    }
#pragma unroll
    for (int t = 0; t < 2; ++t) {
        int col = (wid * 2 + t) * 16 + r0i;
        float bias = b1[col];
#pragma unroll
        for (int r = 0; r < 4; ++r) {
            int hrow = kh * 4 + r;
            float v = fmaxf(acc1[t][r] + bias, 0.0f);
            hl[hrow * 128 + (col ^ ((hrow & 7) << 3))] = f2bf(v);
        }
    }
    __syncthreads();

    f32x4 acc2[2];
    acc2[0] = (f32x4)(0.0f); acc2[1] = (f32x4)(0.0f);
    const short* W2p = Wl + 4 * 8 * 64 * 8;
#pragma unroll
    for (int ks = 0; ks < 4; ++ks) {
        int c0 = ks * 32 + kh * 8;
        bf16x8 af = *(const bf16x8*)&hl[r0i * 128 + (c0 ^ ((r0i & 7) << 3))];
#pragma unroll
        for (int t = 0; t < 2; ++t) {
            int nt = wid * 2 + t;
            bf16x8 bf = *(const bf16x8*)(W2p + ((size_t)(ks * 8 + nt) * 64 + lane) * 8);
            acc2[t] = __builtin_amdgcn_mfma_f32_16x16x32_bf16(af, bf, acc2[t], 0, 0, 0);
        }
    }
#pragma unroll
    for (int t = 0; t < 2; ++t) {
        int col = (wid * 2 + t) * 16 + r0i;
        float bias = b2[col];
#pragma unroll
        for (int r = 0; r < 4; ++r) {
            int orow = rowbase + kh * 4 + r;   // always < N_NODES (exact grid)
            float v = acc2[t][r] + bias;
            if (last) outf[(size_t)orow * D + col] = v;
            else      outbf[(size_t)orow * D + col] = f2bf(v);
        }
    }
}

extern "C" void kernel_launch(void* const* d_in, const int* in_sizes, int n_in,
                              void* d_out, int out_size, void* d_ws, size_t ws_size,
                              hipStream_t stream) {
    const float* h   = (const float*)d_in[0];
    const int*   src = (const int*)d_in[1];
    const int*   dst = (const int*)d_in[2];
    const float* W1  = (const float*)d_in[3];
    const float* b1  = (const float*)d_in[4];
    const float* W2  = (const float*)d_in[5];
    const float* b2  = (const float*)d_in[6];
    const float* eps = (const float*)d_in[7];
    float* out = (float*)d_out;

    char* ws = (char*)d_ws;
    const size_t MB = 1024 * 1024;
    short* hbfA = (short*)ws;                        // 12.8 MB
    short* hbfB = (short*)(ws + 13 * MB);            // 12.8 MB
    short* Wswz = (short*)(ws + 26 * MB);            // 196 KB
    char*  p    = ws + 27 * MB;
    int* off    = (int*)p;                 p += (size_t)(N_NODES + 1) * 4;
    int* bcnt   = (int*)p;                 p += (size_t)NBKT * 4;
    int* bbase  = (int*)p;                 p += (size_t)(NBKT + 1) * 4;
    int* bcur   = (int*)p;                 p += (size_t)NBKT * 4;
    p = (char*)(((uintptr_t)p + 255) & ~(uintptr_t)255);
    int* esrc   = (int*)p;                 p += (size_t)N_EDGES * 4;   // 3.2 MB
    int2* pairs = (int2*)p;                                            // 6.4 MB

    wconv<<<48, 256, 0, stream>>>(W1, W2, Wswz);
    h2bf<<<(N_NODES * D / 8 + 255) / 256, 256, 0, stream>>>(h, hbfA);
    zero_int<<<(NBKT + 255) / 256, 256, 0, stream>>>(bcnt, NBKT);
    bucket_hist<<<BKT_BLOCKS, 256, 0, stream>>>(dst, bcnt);
    bucket_scan<<<1, 512, 0, stream>>>(bcnt, bbase, bcur);
    bucket_scatter<<<BKT_BLOCKS, 256, 0, stream>>>(src, dst, bcur, pairs);
    csr_build<<<NBKT, 256, 0, stream>>>(pairs, bbase, off, esrc);

    const short* hin[3]   = {hbfA, hbfB, hbfA};
    short*      houtbf[3] = {hbfB, hbfA, nullptr};
    const int layer_blocks = N_NODES / 16;           // 3125, exact

    for (int l = 0; l < NLAYER; ++l) {
        gin_layer<<<layer_blocks, 256, 0, stream>>>(hin[l], off, esrc,
                                                    Wswz + (size_t)l * 2 * 16384,
                                                    b1 + (size_t)l * D, b2 + (size_t)l * D,
                                                    eps, l, out, houtbf[l],
                                                    l == NLAYER - 1 ? 1 : 0);
    }
}

// Round 6
// 168.231 us; speedup vs baseline: 24.4963x; 1.0643x over previous
//
#include <hip/hip_runtime.h>
#include <hip/hip_bf16.h>
#include <stdint.h>

#define N_NODES 50000
#define N_EDGES 800000
#define D 128
#define NLAYER 3

#define BKT_SHIFT 7
#define NBKT ((N_NODES + 127) / 128)          // 391 buckets of 128 nodes
#define EPB 4096
#define BKT_BLOCKS ((N_EDGES + EPB - 1) / EPB) // 196
#define CAP 3072

typedef __attribute__((ext_vector_type(8))) short bf16x8;
typedef __attribute__((ext_vector_type(4))) float f32x4;

__device__ __forceinline__ short f2bf(float f) {
    union { float f; uint32_t u; } v; v.f = f;
    uint32_t u = v.u;
    uint32_t r = u + 0x7fffu + ((u >> 16) & 1u);   // round-to-nearest-even
    return (short)(r >> 16);
}
__device__ __forceinline__ float bf2f(short s) {
    union { uint32_t u; float f; } v;
    v.u = ((uint32_t)(uint16_t)s) << 16;
    return v.f;
}

// ---------------------------------------------------------------------------
// Weight conversion: bf16, B-fragment-swizzled (one 16B load per lane-frag).
// ---------------------------------------------------------------------------
__global__ void wconv(const float* __restrict__ W1, const float* __restrict__ W2,
                      short* __restrict__ Wswz) {
    int t = blockIdx.x * blockDim.x + threadIdx.x;   // (l,mat,ks,nt,lane)
    if (t >= NLAYER * 2 * 4 * 8 * 64) return;
    int lane = t & 63;
    int nt   = (t >> 6) & 7;
    int ks   = (t >> 9) & 3;
    int mat  = (t >> 11) & 1;
    int l    = t >> 12;
    const float* W = (mat == 0 ? W1 : W2) + (size_t)l * D * D;
    int n = nt * 16 + (lane & 15);
    short* outp = Wswz + (size_t)t * 8;
#pragma unroll
    for (int j = 0; j < 8; ++j) {
        int k = ks * 32 + (lane >> 4) * 8 + j;
        outp[j] = f2bf(W[k * D + n]);
    }
}

// h (f32) -> hbf (bf16)
__global__ void h2bf(const float* __restrict__ h, short* __restrict__ hbf) {
    int t = blockIdx.x * blockDim.x + threadIdx.x;
    if (t >= N_NODES * D / 8) return;
    f32x4 a = ((const f32x4*)h)[2 * t];
    f32x4 b = ((const f32x4*)h)[2 * t + 1];
    bf16x8 o;
    o[0] = f2bf(a.x); o[1] = f2bf(a.y); o[2] = f2bf(a.z); o[3] = f2bf(a.w);
    o[4] = f2bf(b.x); o[5] = f2bf(b.y); o[6] = f2bf(b.z); o[7] = f2bf(b.w);
    ((bf16x8*)hbf)[t] = o;
}

__global__ void zero_int(int* __restrict__ p, int n) {
    int i = blockIdx.x * blockDim.x + threadIdx.x;
    if (i < n) p[i] = 0;
}

// ---------------------------------------------------------------------------
// CSR build, two-level bucket counting sort. Emits:
//   esrc[e] = src-row BYTE offset (src*256), edst[e] = dst & 15
// ---------------------------------------------------------------------------
__global__ __launch_bounds__(256) void bucket_hist(const int* __restrict__ dst,
                                                   int* __restrict__ bcnt) {
    __shared__ int hcnt[NBKT];
    for (int i = threadIdx.x; i < NBKT; i += 256) hcnt[i] = 0;
    __syncthreads();
    int base = blockIdx.x * EPB;
    int end = base + EPB; if (end > N_EDGES) end = N_EDGES;
    for (int e = base + threadIdx.x; e < end; e += 256)
        atomicAdd(&hcnt[dst[e] >> BKT_SHIFT], 1);
    __syncthreads();
    for (int i = threadIdx.x; i < NBKT; i += 256)
        if (hcnt[i]) atomicAdd(&bcnt[i], hcnt[i]);
}

__global__ __launch_bounds__(512) void bucket_scan(const int* __restrict__ bcnt,
                                                   int* __restrict__ bbase,
                                                   int* __restrict__ bcur) {
    __shared__ int tmp[512];
    int v = (threadIdx.x < NBKT) ? bcnt[threadIdx.x] : 0;
    tmp[threadIdx.x] = v;
    __syncthreads();
#pragma unroll
    for (int s = 1; s < 512; s <<= 1) {
        int t = (threadIdx.x >= s) ? tmp[threadIdx.x - s] : 0;
        __syncthreads();
        tmp[threadIdx.x] += t;
        __syncthreads();
    }
    if (threadIdx.x < NBKT) {
        int b = tmp[threadIdx.x] - v;       // exclusive
        bbase[threadIdx.x] = b;
        bcur[threadIdx.x]  = b;
    }
    if (threadIdx.x == 0) bbase[NBKT] = N_EDGES;
}

__global__ __launch_bounds__(256) void bucket_scatter(const int* __restrict__ src,
                                                      const int* __restrict__ dst,
                                                      int* __restrict__ bcur,
                                                      int2* __restrict__ pairs) {
    __shared__ int hcnt[NBKT];
    __shared__ int hbase[NBKT];
    for (int i = threadIdx.x; i < NBKT; i += 256) hcnt[i] = 0;
    __syncthreads();
    int base = blockIdx.x * EPB;
    int end = base + EPB; if (end > N_EDGES) end = N_EDGES;
    for (int e = base + threadIdx.x; e < end; e += 256)
        atomicAdd(&hcnt[dst[e] >> BKT_SHIFT], 1);
    __syncthreads();
    for (int i = threadIdx.x; i < NBKT; i += 256) {
        int c = hcnt[i];
        hbase[i] = c ? atomicAdd(&bcur[i], c) : 0;
        hcnt[i] = 0;                         // reuse as local rank cursor
    }
    __syncthreads();
    for (int e = base + threadIdx.x; e < end; e += 256) {
        int d = dst[e];
        int b = d >> BKT_SHIFT;
        int r = atomicAdd(&hcnt[b], 1);
        pairs[(size_t)hbase[b] + r] = make_int2(src[e], d);
    }
}

__global__ __launch_bounds__(256) void csr_build(const int2* __restrict__ pairs,
                                                 const int* __restrict__ bbase,
                                                 int* __restrict__ off,
                                                 int* __restrict__ esrc,
                                                 unsigned char* __restrict__ edst) {
    __shared__ int ncnt[128];
    __shared__ int noff[129];
    __shared__ int esl[CAP];
    __shared__ unsigned char dsl[CAP];
    const int b = blockIdx.x;
    const int lo = bbase[b], hi = bbase[b + 1];
    const int n0 = b << BKT_SHIFT;
    const int nN = (N_NODES - n0 < 128) ? (N_NODES - n0) : 128;

    if (threadIdx.x < 128) ncnt[threadIdx.x] = 0;
    __syncthreads();
    for (int e = lo + threadIdx.x; e < hi; e += 256)
        atomicAdd(&ncnt[pairs[e].y & 127], 1);
    __syncthreads();

    if (threadIdx.x < 128) noff[threadIdx.x + 1] = ncnt[threadIdx.x];
    if (threadIdx.x == 0) noff[0] = 0;
    __syncthreads();
#pragma unroll
    for (int s = 1; s < 256; s <<= 1) {
        int t = (threadIdx.x < 129 && threadIdx.x >= s) ? noff[threadIdx.x - s] : 0;
        __syncthreads();
        if (threadIdx.x < 129) noff[threadIdx.x] += t;
        __syncthreads();
    }

    if (threadIdx.x < nN) off[n0 + threadIdx.x] = lo + noff[threadIdx.x];
    if (b == 0 && threadIdx.x == 0) off[N_NODES] = N_EDGES;

    if (threadIdx.x < 128) ncnt[threadIdx.x] = noff[threadIdx.x];  // rank cursors
    __syncthreads();

    const int cnt = hi - lo;
    if (cnt <= CAP) {
        for (int e = lo + threadIdx.x; e < hi; e += 256) {
            int2 p = pairs[e];
            int r = atomicAdd(&ncnt[p.y & 127], 1);
            esl[r] = p.x << 8;
            dsl[r] = (unsigned char)(p.y & 15);
        }
        __syncthreads();
        for (int i = threadIdx.x; i < cnt; i += 256) {
            esrc[lo + i] = esl[i];
            edst[lo + i] = dsl[i];
        }
    } else {  // overflow fallback (not expected at Poisson(2048) vs CAP=3072)
        for (int e = lo + threadIdx.x; e < hi; e += 256) {
            int2 p = pairs[e];
            int r = atomicAdd(&ncnt[p.y & 127], 1);
            esrc[(size_t)lo + r] = p.x << 8;
            edst[(size_t)lo + r] = (unsigned char)(p.y & 15);
        }
    }
}

// ---------------------------------------------------------------------------
// Fused GIN layer, MFMA-based aggregation.
// Block = 16 nodes. Edge range is chunks of 32; each chunk:
//   stage 32 h-rows -> LDS via global_load_lds (subtiled [4][16] layout),
//   A = segment mask (dst==node), B = staged rows via ds_read_b64_tr_b16,
//   acc += A*B  (one mfma per 16-col tile; wave owns 2 tiles = 32 cols).
// Self term (1+eps)*h = one diagonal-mask chunk. Then the 2-stage MLP.
// ---------------------------------------------------------------------------
__global__ __launch_bounds__(256) void gin_layer(const short* __restrict__ hbf,
                                                 const int* __restrict__ off,
                                                 const int* __restrict__ esrc,
                                                 const unsigned char* __restrict__ edst,
                                                 const short* __restrict__ Wl,
                                                 const float* __restrict__ b1,
                                                 const float* __restrict__ b2,
                                                 const float* __restrict__ eps, int l,
                                                 float* __restrict__ outf,
                                                 short* __restrict__ outbf, int last) {
    __shared__ short stg[4096];      // 8KB: [kc 0..7][subtile s 0..7][row 0..3][col 0..15]
    __shared__ short zl[16 * 128];
    __shared__ short hl[16 * 128];

    const int lane = threadIdx.x & 63;
    const int wid  = threadIdx.x >> 6;
    const int n0   = blockIdx.x * 16;
    const int m    = lane & 15;          // A-row (node) / B-col / C-col
    const int kh   = lane >> 4;          // k-quarter

    // staging lane -> (edge slot, col half): lane dest = kcblock + lane*16B
    const int s_    = lane >> 3;                       // subtile 0..7
    const int kr_   = 2 * (s_ & 3) + (s_ >> 2);        // k-row group
    const int eL    = kr_ * 4 + ((lane & 7) >> 1);     // edge slot 0..31
    const int chalf = lane & 1;
    const int kcA   = wid * 2, kcB = wid * 2 + 1;

    const char* hby = (const char*)hbf;
    const int lo  = off[n0];
    const int cnt = off[n0 + 16] - lo;
    const int nch = (cnt + 31) >> 5;
    const short epsbf = f2bf(1.0f + eps[l]);

    const uint32_t stg_base = (uint32_t)(uintptr_t)(__attribute__((address_space(3))) short*)stg;

    f32x4 acc[2];
    acc[0] = (f32x4)(0.0f); acc[1] = (f32x4)(0.0f);

    auto stage2 = [&](const char* gp) {
        __builtin_amdgcn_global_load_lds(
            (const __attribute__((address_space(1))) void*)(gp + kcA * 32),
            (__attribute__((address_space(3))) void*)(stg + kcA * 512), 16, 0, 0);
        __builtin_amdgcn_global_load_lds(
            (const __attribute__((address_space(1))) void*)(gp + kcB * 32),
            (__attribute__((address_space(3))) void*)(stg + kcB * 512), 16, 0, 0);
    };

    auto mfma_tiles = [&](bf16x8 am) {
#pragma unroll
        for (int t = 0; t < 2; ++t) {
            uint32_t a0 = stg_base + (uint32_t)((wid * 2 + t) * 1024 + lane * 8);
            uint64_t r0, r1;
            asm volatile("ds_read_b64_tr_b16 %0, %1" : "=v"(r0) : "v"(a0));
            asm volatile("ds_read_b64_tr_b16 %0, %1 offset:512" : "=v"(r1) : "v"(a0));
            asm volatile("s_waitcnt lgkmcnt(0)" ::: "memory");
            __builtin_amdgcn_sched_barrier(0);
            union { uint64_t u[2]; bf16x8 v; } bb;
            bb.u[0] = r0; bb.u[1] = r1;
            acc[t] = __builtin_amdgcn_mfma_f32_16x16x32_bf16(am, bb.v, acc[t], 0, 0, 0);
        }
    };

    // ---- self chunk: stage rows n0..n0+15, diagonal (1+eps) mask ----
    {
        int e = (eL < 16) ? eL : 0;
        stage2(hby + (size_t)(n0 + e) * 256 + chalf * 16);
    }
    // prefetch chunk-0 indices
    int esv = 0, dsv = 255;
    if (nch > 0) {
        { int ke = eL;        bool v = ke < cnt; int t = esrc[lo + (v ? ke : 0)]; esv = v ? t : 0; }
        { int ke = lane & 31; bool v = ke < cnt; int t = edst[lo + (v ? ke : 0)]; dsv = v ? t : 255; }
    }
    __syncthreads();
    {
        bf16x8 am;
#pragma unroll
        for (int e = 0; e < 8; ++e) am[e] = ((kh * 8 + e) == m) ? epsbf : (short)0;
        mfma_tiles(am);
    }
    __syncthreads();

    // ---- edge chunks ----
    for (int c = 0; c < nch; ++c) {
        stage2(hby + (size_t)(uint32_t)esv + chalf * 16);
        int esvN = 0, dsvN = 255;
        if (c + 1 < nch) {
            int kb = (c + 1) * 32;
            { int ke = kb + eL;          bool v = ke < cnt; int t = esrc[lo + (v ? ke : 0)]; esvN = v ? t : 0; }
            { int ke = kb + (lane & 31); bool v = ke < cnt; int t = edst[lo + (v ? ke : 0)]; dsvN = v ? t : 255; }
        }
        __syncthreads();
        bf16x8 am;
#pragma unroll
        for (int e = 0; e < 8; ++e) {
            int dk = __shfl(dsv, kh * 8 + e, 64);
            am[e] = (dk == m) ? (short)0x3F80 : (short)0;
        }
        mfma_tiles(am);
        __syncthreads();
        esv = esvN; dsv = dsvN;
    }

    // ---- z (C layout) -> zl LDS, granule-swizzled for MLP A-frags ----
#pragma unroll
    for (int t = 0; t < 2; ++t) {
        int col = (wid * 2 + t) * 16 + m;
        int gi = col >> 3, ci = col & 7;
#pragma unroll
        for (int r = 0; r < 4; ++r) {
            int row = kh * 4 + r;
            zl[row * 128 + ((gi ^ (row & 7)) << 3) + ci] = f2bf(acc[t][r]);
        }
    }
    __syncthreads();

    // ---- MLP stage 1: hid = relu(z @ W1 + b1) ----
    f32x4 acc1[2];
    acc1[0] = (f32x4)(0.0f); acc1[1] = (f32x4)(0.0f);
#pragma unroll
    for (int ks = 0; ks < 4; ++ks) {
        int gidx = ks * 4 + kh;
        bf16x8 af = *(const bf16x8*)&zl[m * 128 + ((gidx ^ (m & 7)) * 8)];
#pragma unroll
        for (int t = 0; t < 2; ++t) {
            int nt = wid * 2 + t;
            bf16x8 bf = *(const bf16x8*)(Wl + ((size_t)(ks * 8 + nt) * 64 + lane) * 8);
            acc1[t] = __builtin_amdgcn_mfma_f32_16x16x32_bf16(af, bf, acc1[t], 0, 0, 0);
        }
    }
#pragma unroll
    for (int t = 0; t < 2; ++t) {
        int col = (wid * 2 + t) * 16 + m;
        float bias = b1[col];
#pragma unroll
        for (int r = 0; r < 4; ++r) {
            int hrow = kh * 4 + r;
            float v = fmaxf(acc1[t][r] + bias, 0.0f);
            hl[hrow * 128 + (col ^ ((hrow & 7) << 3))] = f2bf(v);
        }
    }
    __syncthreads();

    // ---- MLP stage 2: out = hid @ W2 + b2 ----
    f32x4 acc2[2];
    acc2[0] = (f32x4)(0.0f); acc2[1] = (f32x4)(0.0f);
    const short* W2p = Wl + 4 * 8 * 64 * 8;
#pragma unroll
    for (int ks = 0; ks < 4; ++ks) {
        int c0 = ks * 32 + kh * 8;
        bf16x8 af = *(const bf16x8*)&hl[m * 128 + (c0 ^ ((m & 7) << 3))];
#pragma unroll
        for (int t = 0; t < 2; ++t) {
            int nt = wid * 2 + t;
            bf16x8 bf = *(const bf16x8*)(W2p + ((size_t)(ks * 8 + nt) * 64 + lane) * 8);
            acc2[t] = __builtin_amdgcn_mfma_f32_16x16x32_bf16(af, bf, acc2[t], 0, 0, 0);
        }
    }
#pragma unroll
    for (int t = 0; t < 2; ++t) {
        int col = (wid * 2 + t) * 16 + m;
        float bias = b2[col];
#pragma unroll
        for (int r = 0; r < 4; ++r) {
            int orow = n0 + kh * 4 + r;        // exact grid, always < N_NODES
            float v = acc2[t][r] + bias;
            if (last) outf[(size_t)orow * D + col] = v;
            else      outbf[(size_t)orow * D + col] = f2bf(v);
        }
    }
}

extern "C" void kernel_launch(void* const* d_in, const int* in_sizes, int n_in,
                              void* d_out, int out_size, void* d_ws, size_t ws_size,
                              hipStream_t stream) {
    const float* h   = (const float*)d_in[0];
    const int*   src = (const int*)d_in[1];
    const int*   dst = (const int*)d_in[2];
    const float* W1  = (const float*)d_in[3];
    const float* b1  = (const float*)d_in[4];
    const float* W2  = (const float*)d_in[5];
    const float* b2  = (const float*)d_in[6];
    const float* eps = (const float*)d_in[7];
    float* out = (float*)d_out;

    char* ws = (char*)d_ws;
    const size_t MB = 1024 * 1024;
    short* hbfA = (short*)ws;                        // 12.8 MB
    short* hbfB = (short*)(ws + 13 * MB);            // 12.8 MB
    short* Wswz = (short*)(ws + 26 * MB);            // 196 KB
    char*  p    = ws + 27 * MB;
    int* off    = (int*)p;                 p += (size_t)(N_NODES + 1) * 4;
    int* bcnt   = (int*)p;                 p += (size_t)NBKT * 4;
    int* bbase  = (int*)p;                 p += (size_t)(NBKT + 1) * 4;
    int* bcur   = (int*)p;                 p += (size_t)NBKT * 4;
    p = (char*)(((uintptr_t)p + 255) & ~(uintptr_t)255);
    int* esrc   = (int*)p;                 p += (size_t)N_EDGES * 4;   // 3.2 MB
    unsigned char* edst = (unsigned char*)p; p += (size_t)N_EDGES;     // 0.8 MB
    p = (char*)(((uintptr_t)p + 255) & ~(uintptr_t)255);
    int2* pairs = (int2*)p;                                            // 6.4 MB

    wconv<<<48, 256, 0, stream>>>(W1, W2, Wswz);
    h2bf<<<(N_NODES * D / 8 + 255) / 256, 256, 0, stream>>>(h, hbfA);
    zero_int<<<(NBKT + 255) / 256, 256, 0, stream>>>(bcnt, NBKT);
    bucket_hist<<<BKT_BLOCKS, 256, 0, stream>>>(dst, bcnt);
    bucket_scan<<<1, 512, 0, stream>>>(bcnt, bbase, bcur);
    bucket_scatter<<<BKT_BLOCKS, 256, 0, stream>>>(src, dst, bcur, pairs);
    csr_build<<<NBKT, 256, 0, stream>>>(pairs, bbase, off, esrc, edst);

    const short* hin[3]   = {hbfA, hbfB, hbfA};
    short*      houtbf[3] = {hbfB, hbfA, nullptr};
    const int layer_blocks = N_NODES / 16;           // 3125, exact

    for (int l = 0; l < NLAYER; ++l) {
        gin_layer<<<layer_blocks, 256, 0, stream>>>(hin[l], off, esrc, edst,
                                                    Wswz + (size_t)l * 2 * 16384,
                                                    b1 + (size_t)l * D, b2 + (size_t)l * D,
                                                    eps, l, out, houtbf[l],
                                                    l == NLAYER - 1 ? 1 : 0);
    }
}

// Round 7
// 161.656 us; speedup vs baseline: 25.4926x; 1.0407x over previous
//
#include <hip/hip_runtime.h>
#include <hip/hip_bf16.h>
#include <stdint.h>

#define N_NODES 50000
#define N_EDGES 800000
#define D 128
#define NLAYER 3
#define NGROUP (N_NODES / 16)     // 3125 groups of 16 nodes
#define CAPG 384                   // max edges per group (Poisson(256), +8 sigma)
#define GSTRIDE 448                // segment stride (incl. prefetch slack, 64B-mult)
#define EPB 4096
#define SC_BLOCKS ((N_EDGES + EPB - 1) / EPB)  // 196

typedef __attribute__((ext_vector_type(8))) short bf16x8;
typedef __attribute__((ext_vector_type(4))) float f32x4;

__device__ __forceinline__ short f2bf(float f) {
    union { float f; uint32_t u; } v; v.f = f;
    uint32_t u = v.u;
    uint32_t r = u + 0x7fffu + ((u >> 16) & 1u);   // round-to-nearest-even
    return (short)(r >> 16);
}

// ---------------------------------------------------------------------------
// Weight conversion: bf16, B-fragment-swizzled (one 16B load per lane-frag).
// ---------------------------------------------------------------------------
__global__ void wconv(const float* __restrict__ W1, const float* __restrict__ W2,
                      short* __restrict__ Wswz) {
    int t = blockIdx.x * blockDim.x + threadIdx.x;   // (l,mat,ks,nt,lane)
    if (t >= NLAYER * 2 * 4 * 8 * 64) return;
    int lane = t & 63;
    int nt   = (t >> 6) & 7;
    int ks   = (t >> 9) & 3;
    int mat  = (t >> 11) & 1;
    int l    = t >> 12;
    const float* W = (mat == 0 ? W1 : W2) + (size_t)l * D * D;
    int n = nt * 16 + (lane & 15);
    short* outp = Wswz + (size_t)t * 8;
#pragma unroll
    for (int j = 0; j < 8; ++j) {
        int k = ks * 32 + (lane >> 4) * 8 + j;
        outp[j] = f2bf(W[k * D + n]);
    }
}

// h (f32) -> hbf (bf16)
__global__ void h2bf(const float* __restrict__ h, short* __restrict__ hbf) {
    int t = blockIdx.x * blockDim.x + threadIdx.x;
    if (t >= N_NODES * D / 8) return;
    f32x4 a = ((const f32x4*)h)[2 * t];
    f32x4 b = ((const f32x4*)h)[2 * t + 1];
    bf16x8 o;
    o[0] = f2bf(a.x); o[1] = f2bf(a.y); o[2] = f2bf(a.z); o[3] = f2bf(a.w);
    o[4] = f2bf(b.x); o[5] = f2bf(b.y); o[6] = f2bf(b.z); o[7] = f2bf(b.w);
    ((bf16x8*)hbf)[t] = o;
}

// default-fill the padded edge segments + zero group cursors
__global__ void pad_init(int* __restrict__ esrc, unsigned char* __restrict__ edst,
                         int* __restrict__ gcnt) {
    int i = blockIdx.x * blockDim.x + threadIdx.x;
    const int n = NGROUP * GSTRIDE;
    if (i < n) { esrc[i] = 0; edst[i] = 0xFF; }
    if (i < NGROUP) gcnt[i] = 0;
}

// ---------------------------------------------------------------------------
// Edge binning into fixed-stride per-group segments (LDS two-pass per block).
// esrc[slot] = src row byte offset (src*256); edst[slot] = dst & 15.
// ---------------------------------------------------------------------------
__global__ __launch_bounds__(256) void scatter(const int* __restrict__ src,
                                               const int* __restrict__ dst,
                                               int* __restrict__ gcnt,
                                               int* __restrict__ esrc,
                                               unsigned char* __restrict__ edst) {
    __shared__ int hcnt[NGROUP];
    __shared__ int hbase[NGROUP];
    for (int i = threadIdx.x; i < NGROUP; i += 256) hcnt[i] = 0;
    __syncthreads();
    int base = blockIdx.x * EPB;
    int end = base + EPB; if (end > N_EDGES) end = N_EDGES;
    for (int e = base + threadIdx.x; e < end; e += 256)
        atomicAdd(&hcnt[dst[e] >> 4], 1);
    __syncthreads();
    for (int i = threadIdx.x; i < NGROUP; i += 256) {
        int c = hcnt[i];
        hbase[i] = c ? atomicAdd(&gcnt[i], c) : 0;
        hcnt[i] = 0;                          // reuse as local rank cursor
    }
    __syncthreads();
    for (int e = base + threadIdx.x; e < end; e += 256) {
        int s = src[e], d = dst[e];
        int g = d >> 4;
        int r = atomicAdd(&hcnt[g], 1);
        size_t p = (size_t)g * GSTRIDE + hbase[g] + r;
        esrc[p] = s << 8;
        edst[p] = (unsigned char)(d & 15);
    }
}

// ---------------------------------------------------------------------------
// Fused GIN layer, MFMA aggregation, barrier-free double-buffered pipeline.
// Block = 16 nodes (grid exactly NGROUP), 4 waves; wave owns 32 output cols.
// Per 32-edge chunk: stage rows -> own LDS region (global_load_lds, subtiled
// layout), wait vmcnt(4) (counted: exactly 4 VMEM ops/iter), mask from
// prefetched edst bytes, 2x (tr_read pair + mfma). Self term = diagonal chunk.
// ---------------------------------------------------------------------------
__global__ __launch_bounds__(256) void gin_layer(const short* __restrict__ hbf,
                                                 const int* __restrict__ gcnt,
                                                 const int* __restrict__ esrc,
                                                 const unsigned char* __restrict__ edst,
                                                 const short* __restrict__ Wl,
                                                 const float* __restrict__ b1,
                                                 const float* __restrict__ b2,
                                                 const float* __restrict__ eps, int l,
                                                 float* __restrict__ outf,
                                                 short* __restrict__ outbf, int last) {
    __shared__ union {
        short stg[2][4096];                           // 2 x 8KB staging
        struct { short zl[2048]; short hl[2048]; } t; // MLP tiles (overlay)
    } sm;

    const int lane = threadIdx.x & 63;
    const int wid  = threadIdx.x >> 6;
    const int g    = blockIdx.x;
    const int n0   = g * 16;
    const int m    = lane & 15;          // A-row (node) / C-col
    const int kh   = lane >> 4;          // k-quarter

    // staging lane -> (edge slot, col half)
    const int s_    = lane >> 3;
    const int kr_   = 2 * (s_ & 3) + (s_ >> 2);
    const int eL    = kr_ * 4 + ((lane & 7) >> 1);   // edge slot 0..31
    const int chalf = lane & 1;
    const int kcA   = wid * 2, kcB = wid * 2 + 1;

    const char* hby = (const char*)hbf;
    const int lo  = g * GSTRIDE;
    const int cnt = gcnt[g];
    const int nch = (cnt + 31) >> 5;                 // <= 12
    const short epsbf = f2bf(1.0f + eps[l]);
    const short one = (short)0x3F80;

    const uint32_t stg_base =
        (uint32_t)(uintptr_t)(__attribute__((address_space(3))) short*)&sm.stg[0][0];

    f32x4 acc[2];
    acc[0] = (f32x4)(0.0f); acc[1] = (f32x4)(0.0f);

#define STAGE(b, gp) do { \
        const char* _g = (gp); \
        __builtin_amdgcn_global_load_lds( \
            (const __attribute__((address_space(1))) void*)(_g + kcA * 32), \
            (__attribute__((address_space(3))) void*)(&sm.stg[(b)][0] + kcA * 512), 16, 0, 0); \
        __builtin_amdgcn_global_load_lds( \
            (const __attribute__((address_space(1))) void*)(_g + kcB * 32), \
            (__attribute__((address_space(3))) void*)(&sm.stg[(b)][0] + kcB * 512), 16, 0, 0); \
    } while (0)

    auto mfma_tiles = [&](int b, bf16x8 am) {
#pragma unroll
        for (int t = 0; t < 2; ++t) {
            uint32_t a0 = stg_base + (uint32_t)(b * 8192 + (wid * 2 + t) * 1024 + lane * 8);
            uint64_t r0, r1;
            asm volatile("ds_read_b64_tr_b16 %0, %1" : "=v"(r0) : "v"(a0));
            asm volatile("ds_read_b64_tr_b16 %0, %1 offset:512" : "=v"(r1) : "v"(a0));
            asm volatile("s_waitcnt lgkmcnt(0)" ::: "memory");
            __builtin_amdgcn_sched_barrier(0);
            union { uint64_t u[2]; bf16x8 v; } bb;
            bb.u[0] = r0; bb.u[1] = r1;
            acc[t] = __builtin_amdgcn_mfma_f32_16x16x32_bf16(am, bb.v, acc[t], 0, 0, 0);
        }
    };

    const int* ep = esrc + lo;
    const unsigned char* dp = edst + lo;

    // ---- prologue: self chunk -> buf0, chunk0 -> buf1, idx(1) prefetched ----
    {
        int eSelf = (eL < 16) ? eL : 0;
        STAGE(0, hby + (size_t)(n0 + eSelf) * 256 + chalf * 16);
    }
    int e_c0 = ep[eL];
    uint2 d_cur = *(const uint2*)(dp + kh * 8);
    STAGE(1, hby + (size_t)(uint32_t)e_c0 + chalf * 16);
    int e_n1 = ep[32 + eL];
    uint2 d_n1 = *(const uint2*)(dp + 32 + kh * 8);
    asm volatile("s_waitcnt vmcnt(4)" ::: "memory");
    __builtin_amdgcn_sched_barrier(0);
    {
        bf16x8 am;
#pragma unroll
        for (int e = 0; e < 8; ++e) am[e] = ((kh * 8 + e) == m) ? epsbf : (short)0;
        mfma_tiles(0, am);
    }

    // ---- steady loop: exactly 4 VMEM ops per iter between counted waits ----
    for (int c = 0; c < nch; ++c) {
        STAGE(c & 1, hby + (size_t)(uint32_t)e_n1 + chalf * 16);   // chunk c+1
        int e_n2 = ep[(c + 2) * 32 + eL];                          // in padded slack
        uint2 d_n2 = *(const uint2*)(dp + (c + 2) * 32 + kh * 8);
        asm volatile("s_waitcnt vmcnt(4)" ::: "memory");
        __builtin_amdgcn_sched_barrier(0);
        bf16x8 am;
        uint32_t dx = d_cur.x, dy = d_cur.y;
#pragma unroll
        for (int e = 0; e < 4; ++e) {
            am[e]     = (((dx >> (e * 8)) & 255u) == (uint32_t)m) ? one : (short)0;
            am[e + 4] = (((dy >> (e * 8)) & 255u) == (uint32_t)m) ? one : (short)0;
        }
        mfma_tiles((c + 1) & 1, am);
        e_n1 = e_n2; d_cur = d_n1; d_n1 = d_n2;
    }

    __syncthreads();   // all waves done with stg; safe to overlay zl/hl

    // ---- z (C layout) -> zl LDS, granule-swizzled for MLP A-frags ----
#pragma unroll
    for (int t = 0; t < 2; ++t) {
        int col = (wid * 2 + t) * 16 + m;
        int gi = col >> 3, ci = col & 7;
#pragma unroll
        for (int r = 0; r < 4; ++r) {
            int row = kh * 4 + r;
            sm.t.zl[row * 128 + ((gi ^ (row & 7)) << 3) + ci] = f2bf(acc[t][r]);
        }
    }
    __syncthreads();

    // ---- MLP stage 1: hid = relu(z @ W1 + b1) ----
    f32x4 acc1[2];
    acc1[0] = (f32x4)(0.0f); acc1[1] = (f32x4)(0.0f);
#pragma unroll
    for (int ks = 0; ks < 4; ++ks) {
        int gidx = ks * 4 + kh;
        bf16x8 af = *(const bf16x8*)&sm.t.zl[m * 128 + ((gidx ^ (m & 7)) * 8)];
#pragma unroll
        for (int t = 0; t < 2; ++t) {
            int nt = wid * 2 + t;
            bf16x8 bf = *(const bf16x8*)(Wl + ((size_t)(ks * 8 + nt) * 64 + lane) * 8);
            acc1[t] = __builtin_amdgcn_mfma_f32_16x16x32_bf16(af, bf, acc1[t], 0, 0, 0);
        }
    }
#pragma unroll
    for (int t = 0; t < 2; ++t) {
        int col = (wid * 2 + t) * 16 + m;
        float bias = b1[col];
#pragma unroll
        for (int r = 0; r < 4; ++r) {
            int hrow = kh * 4 + r;
            float v = fmaxf(acc1[t][r] + bias, 0.0f);
            sm.t.hl[hrow * 128 + (col ^ ((hrow & 7) << 3))] = f2bf(v);
        }
    }
    __syncthreads();

    // ---- MLP stage 2: out = hid @ W2 + b2 ----
    f32x4 acc2[2];
    acc2[0] = (f32x4)(0.0f); acc2[1] = (f32x4)(0.0f);
    const short* W2p = Wl + 4 * 8 * 64 * 8;
#pragma unroll
    for (int ks = 0; ks < 4; ++ks) {
        int c0 = ks * 32 + kh * 8;
        bf16x8 af = *(const bf16x8*)&sm.t.hl[m * 128 + (c0 ^ ((m & 7) << 3))];
#pragma unroll
        for (int t = 0; t < 2; ++t) {
            int nt = wid * 2 + t;
            bf16x8 bf = *(const bf16x8*)(W2p + ((size_t)(ks * 8 + nt) * 64 + lane) * 8);
            acc2[t] = __builtin_amdgcn_mfma_f32_16x16x32_bf16(af, bf, acc2[t], 0, 0, 0);
        }
    }
#pragma unroll
    for (int t = 0; t < 2; ++t) {
        int col = (wid * 2 + t) * 16 + m;
        float bias = b2[col];
#pragma unroll
        for (int r = 0; r < 4; ++r) {
            int orow = n0 + kh * 4 + r;        // exact grid, always < N_NODES
            float v = acc2[t][r] + bias;
            if (last) outf[(size_t)orow * D + col] = v;
            else      outbf[(size_t)orow * D + col] = f2bf(v);
        }
    }
#undef STAGE
}

extern "C" void kernel_launch(void* const* d_in, const int* in_sizes, int n_in,
                              void* d_out, int out_size, void* d_ws, size_t ws_size,
                              hipStream_t stream) {
    const float* h   = (const float*)d_in[0];
    const int*   src = (const int*)d_in[1];
    const int*   dst = (const int*)d_in[2];
    const float* W1  = (const float*)d_in[3];
    const float* b1  = (const float*)d_in[4];
    const float* W2  = (const float*)d_in[5];
    const float* b2  = (const float*)d_in[6];
    const float* eps = (const float*)d_in[7];
    float* out = (float*)d_out;

    char* ws = (char*)d_ws;
    const size_t MB = 1024 * 1024;
    short* hbfA = (short*)ws;                          // 12.8 MB
    short* hbfB = (short*)(ws + 13 * MB);              // 12.8 MB
    short* Wswz = (short*)(ws + 26 * MB);              // 196 KB
    int*   gcnt = (int*)(ws + 27 * MB);                // 12.5 KB
    int*   esrc = (int*)(ws + 28 * MB);                // 5.6 MB
    unsigned char* edst = (unsigned char*)(ws + 34 * MB);  // 1.4 MB

    wconv<<<48, 256, 0, stream>>>(W1, W2, Wswz);
    h2bf<<<(N_NODES * D / 8 + 255) / 256, 256, 0, stream>>>(h, hbfA);
    pad_init<<<(NGROUP * GSTRIDE + 255) / 256, 256, 0, stream>>>(esrc, edst, gcnt);
    scatter<<<SC_BLOCKS, 256, 0, stream>>>(src, dst, gcnt, esrc, edst);

    const short* hin[3]   = {hbfA, hbfB, hbfA};
    short*      houtbf[3] = {hbfB, hbfA, nullptr};

    for (int l = 0; l < NLAYER; ++l) {
        gin_layer<<<NGROUP, 256, 0, stream>>>(hin[l], gcnt, esrc, edst,
                                              Wswz + (size_t)l * 2 * 16384,
                                              b1 + (size_t)l * D, b2 + (size_t)l * D,
                                              eps, l, out, houtbf[l],
                                              l == NLAYER - 1 ? 1 : 0);
    }
}